// Round 1
// baseline (527.381 us; speedup 1.0000x reference)
//
#include <hip/hip_runtime.h>
#include <math.h>

#define N_NODES 30000
#define N_EDGES 480000
#define IN_FEATS 256
#define N_HEADS 8
#define OUT_FEATS 32
#define EDGE_FEATS 64
#define NUM_ETYPES 8
#define NEG_SLOPE 0.2f
#define HD 256  // N_HEADS*OUT_FEATS

// ---------------------------------------------------------------------------
// Kernel 1: edge-type MLP collapsed to an 8x8 table ee[type][head].
// e_proc depends only on e_feat (8 values) -> precompute once.
// ---------------------------------------------------------------------------
__global__ void precompute_ee(const float* __restrict__ edge_emb,
                              const float* __restrict__ W1, const float* __restrict__ b1,
                              const float* __restrict__ W2, const float* __restrict__ b2,
                              const float* __restrict__ attn_e,
                              float* __restrict__ ee_table) {
    __shared__ float h1[NUM_ETYPES][2 * EDGE_FEATS];          // 8 x 128
    __shared__ float h2[NUM_ETYPES][N_HEADS * EDGE_FEATS];    // 8 x 512
    const int tid = threadIdx.x;          // 512 threads
    const int t = tid >> 6;               // etype 0..7
    const int j = tid & 63;               // 0..63

    #pragma unroll
    for (int rr = 0; rr < 2; rr++) {
        int row = j + rr * 64;            // 0..127
        float s = b1[row];
        for (int k = 0; k < EDGE_FEATS; k++)
            s = fmaf(W1[row * EDGE_FEATS + k], edge_emb[t * EDGE_FEATS + k], s);
        h1[t][row] = fmaxf(s, 0.f);
    }
    __syncthreads();
    #pragma unroll
    for (int rr = 0; rr < 8; rr++) {
        int row = j * 8 + rr;             // 0..511
        float s = b2[row];
        for (int k = 0; k < 2 * EDGE_FEATS; k++)
            s = fmaf(W2[row * 2 * EDGE_FEATS + k], h1[t][k], s);
        h2[t][row] = s;
    }
    __syncthreads();
    if (j < N_HEADS) {
        float s = 0.f;
        for (int f = 0; f < EDGE_FEATS; f++)
            s = fmaf(h2[t][j * EDGE_FEATS + f], attn_e[j * EDGE_FEATS + f], s);
        ee_table[t * N_HEADS + j] = s;
    }
}

// ---------------------------------------------------------------------------
// Kernel 2: feat_src = feat @ fc_W^T   (fp32 tiled GEMM, correctness-first)
// A: [M,K] row-major, B: fc_W [N,K] row-major (i.e. B^T layout -> ideal)
// ---------------------------------------------------------------------------
#define BM 64
#define BN 64
#define BK 16
__global__ __launch_bounds__(256) void gemm_fc(const float* __restrict__ A,
                                               const float* __restrict__ B,
                                               float* __restrict__ C) {
    __shared__ float As[BK][BM + 1];
    __shared__ float Bs[BK][BN + 1];
    const int tid = threadIdx.x;
    const int tx = tid & 15;
    const int ty = tid >> 4;
    const int row0 = blockIdx.x * BM;
    const int col0 = blockIdx.y * BN;
    const int lr = tid >> 2;            // 0..63
    const int lk = (tid & 3) << 2;      // 0,4,8,12
    float acc[4][4] = {};

    for (int k0 = 0; k0 < IN_FEATS; k0 += BK) {
        float4 av = make_float4(0.f, 0.f, 0.f, 0.f);
        int arow = row0 + lr;
        if (arow < N_NODES)
            av = *(const float4*)(A + (size_t)arow * IN_FEATS + k0 + lk);
        As[lk + 0][lr] = av.x; As[lk + 1][lr] = av.y;
        As[lk + 2][lr] = av.z; As[lk + 3][lr] = av.w;
        float4 bv = *(const float4*)(B + (size_t)(col0 + lr) * IN_FEATS + k0 + lk);
        Bs[lk + 0][lr] = bv.x; Bs[lk + 1][lr] = bv.y;
        Bs[lk + 2][lr] = bv.z; Bs[lk + 3][lr] = bv.w;
        __syncthreads();
        #pragma unroll
        for (int kk = 0; kk < BK; kk++) {
            float a[4], b[4];
            #pragma unroll
            for (int i = 0; i < 4; i++) a[i] = As[kk][ty * 4 + i];
            #pragma unroll
            for (int j = 0; j < 4; j++) b[j] = Bs[kk][tx * 4 + j];
            #pragma unroll
            for (int i = 0; i < 4; i++)
                #pragma unroll
                for (int j = 0; j < 4; j++)
                    acc[i][j] = fmaf(a[i], b[j], acc[i][j]);
        }
        __syncthreads();
    }
    #pragma unroll
    for (int i = 0; i < 4; i++) {
        int row = row0 + ty * 4 + i;
        if (row >= N_NODES) break;
        *(float4*)(C + (size_t)row * HD + col0 + tx * 4) =
            make_float4(acc[i][0], acc[i][1], acc[i][2], acc[i][3]);
    }
}

// ---------------------------------------------------------------------------
// Kernel 3: el[n,h] = sum_d feat_src[n,h,d]*attn_l[h,d]; er likewise
// ---------------------------------------------------------------------------
__global__ void el_er_kernel(const float* __restrict__ feat_src,
                             const float* __restrict__ attn_l,
                             const float* __restrict__ attn_r,
                             float* __restrict__ el, float* __restrict__ er) {
    int i = blockIdx.x * blockDim.x + threadIdx.x;   // n*8+h
    if (i >= N_NODES * N_HEADS) return;
    int h = i & 7;
    const float* fs = feat_src + (size_t)i * OUT_FEATS;
    const float* al = attn_l + h * OUT_FEATS;
    const float* ar = attn_r + h * OUT_FEATS;
    float sl = 0.f, sr = 0.f;
    #pragma unroll
    for (int d4 = 0; d4 < OUT_FEATS; d4 += 4) {
        float4 v = *(const float4*)(fs + d4);
        float4 a = *(const float4*)(al + d4);
        float4 b = *(const float4*)(ar + d4);
        sl += v.x * a.x + v.y * a.y + v.z * a.z + v.w * a.w;
        sr += v.x * b.x + v.y * b.y + v.z * b.z + v.w * b.w;
    }
    el[i] = sl; er[i] = sr;
}

// ordered-int transform for float atomicMax
__device__ __forceinline__ unsigned f2ord(float f) {
    unsigned b = __float_as_uint(f);
    return ((int)b >= 0) ? (b | 0x80000000u) : ~b;
}
__device__ __forceinline__ float ord2f(unsigned u) {
    unsigned b = (u & 0x80000000u) ? (u ^ 0x80000000u) : ~u;
    return __uint_as_float(b);
}

// ---------------------------------------------------------------------------
// Kernel 4: per-(edge,head) logits -> aOut scratch; atomicMax per (dst,head);
//           histogram of dst (h==0 lanes)
// ---------------------------------------------------------------------------
__global__ void logits_kernel(const int* __restrict__ src, const int* __restrict__ dst,
                              const int* __restrict__ etype,
                              const float* __restrict__ el, const float* __restrict__ er,
                              const float* __restrict__ ee_table, const float* __restrict__ w_r,
                              float* __restrict__ logits, unsigned* __restrict__ nmax,
                              int* __restrict__ counts) {
    int i = blockIdx.x * blockDim.x + threadIdx.x;
    if (i >= N_EDGES * N_HEADS) return;
    int e = i >> 3, h = i & 7;
    int s = src[e], d = dst[e], t = etype[e];
    float x = el[s * 8 + h] + er[d * 8 + h] + ee_table[t * 8 + h];
    x = (x > 0.f) ? x : NEG_SLOPE * x;
    x *= w_r[t];
    logits[i] = x;
    atomicMax(&nmax[d * 8 + h], f2ord(x));
    if (h == 0) atomicAdd(&counts[d], 1);
}

// Kernel 5: ex = exp(logit - max); atomicAdd denom
__global__ void exp_kernel(const int* __restrict__ dst, const unsigned* __restrict__ nmax,
                           float* __restrict__ exbuf, float* __restrict__ denom) {
    int i = blockIdx.x * blockDim.x + threadIdx.x;
    if (i >= N_EDGES * N_HEADS) return;
    int e = i >> 3, h = i & 7;
    int d = dst[e];
    float m = ord2f(nmax[d * 8 + h]);
    float v = __expf(exbuf[i] - m);
    exbuf[i] = v;
    atomicAdd(&denom[d * 8 + h], v);
}

// Kernel 6: a = ex / denom[dst]
__global__ void norm_kernel(const int* __restrict__ dst, const float* __restrict__ denom,
                            float* __restrict__ a) {
    int i = blockIdx.x * blockDim.x + threadIdx.x;
    if (i >= N_EDGES * N_HEADS) return;
    int e = i >> 3, h = i & 7;
    a[i] = a[i] / denom[dst[e] * 8 + h];
}

// ---------------------------------------------------------------------------
// Kernel 7: exclusive scan of counts -> offsets (+ cursor copy). One block.
// Each thread serially handles a contiguous chunk; one block-wide scan.
// ---------------------------------------------------------------------------
__global__ void scan_kernel(const int* __restrict__ counts, int* __restrict__ offsets,
                            int* __restrict__ cursor) {
    __shared__ int sums[1024];
    const int T = 1024;
    const int per = (N_NODES + T - 1) / T;   // 30
    int t = threadIdx.x;
    int beg = t * per;
    int end = beg + per; if (end > N_NODES) end = N_NODES;
    int s = 0;
    for (int i = beg; i < end; i++) s += counts[i];
    sums[t] = s;
    __syncthreads();
    for (int off = 1; off < T; off <<= 1) {
        int v = (t >= off) ? sums[t - off] : 0;
        __syncthreads();
        sums[t] += v;
        __syncthreads();
    }
    int run = sums[t] - s;   // exclusive prefix of this chunk
    for (int i = beg; i < end; i++) {
        offsets[i] = run; cursor[i] = run;
        run += counts[i];
    }
}

// Kernel 8: scatter edge ids into CSR order
__global__ void scatter_kernel(const int* __restrict__ dst, int* __restrict__ cursor,
                               int* __restrict__ sorted_eid) {
    int e = blockIdx.x * blockDim.x + threadIdx.x;
    if (e >= N_EDGES) return;
    int pos = atomicAdd(&cursor[dst[e]], 1);
    sorted_eid[pos] = e;
}

// ---------------------------------------------------------------------------
// Kernel 9: per-dst aggregation. One wave per node; 64 lanes x 4 = 256 (h,d).
// rst[v,h,d] = sum_e a[e,h] * feat_src[src_e,h,d]
// ---------------------------------------------------------------------------
__global__ __launch_bounds__(256) void aggregate_kernel(const int* __restrict__ offsets,
                                                        const int* __restrict__ counts,
                                                        const int* __restrict__ sorted_eid,
                                                        const int* __restrict__ src,
                                                        const float* __restrict__ feat_src,
                                                        const float* __restrict__ aOut,
                                                        float* __restrict__ rst) {
    int node = (blockIdx.x * blockDim.x + threadIdx.x) >> 6;
    int lane = threadIdx.x & 63;
    if (node >= N_NODES) return;
    int beg = offsets[node], cnt = counts[node];
    float acc[4] = {0.f, 0.f, 0.f, 0.f};
    for (int k = 0; k < cnt; k++) {
        int eid = sorted_eid[beg + k];
        int s = src[eid];
        const float* fs = feat_src + (size_t)s * HD;
        const float* ap = aOut + (size_t)eid * N_HEADS;
        #pragma unroll
        for (int i = 0; i < 4; i++) {
            int p = lane + 64 * i;            // h = p>>5, d = p&31
            acc[i] = fmaf(ap[p >> 5], fs[p], acc[i]);
        }
    }
    float* out = rst + (size_t)node * HD;
    #pragma unroll
    for (int i = 0; i < 4; i++) out[lane + 64 * i] = acc[i];
}

// ---------------------------------------------------------------------------
extern "C" void kernel_launch(void* const* d_in, const int* in_sizes, int n_in,
                              void* d_out, int out_size, void* d_ws, size_t ws_size,
                              hipStream_t stream) {
    const float* feat     = (const float*)d_in[0];
    const int*   e_feat   = (const int*)  d_in[1];
    const int*   src      = (const int*)  d_in[2];
    const int*   dst      = (const int*)  d_in[3];
    const float* fc_W     = (const float*)d_in[4];
    const float* edge_emb = (const float*)d_in[5];
    const float* w_r      = (const float*)d_in[6];
    const float* W1       = (const float*)d_in[7];
    const float* b1       = (const float*)d_in[8];
    const float* W2       = (const float*)d_in[9];
    const float* b2       = (const float*)d_in[10];
    const float* attn_l   = (const float*)d_in[11];
    const float* attn_r   = (const float*)d_in[12];
    const float* attn_e   = (const float*)d_in[13];

    char* ws = (char*)d_ws;
    float*    feat_src = (float*)   (ws + 0);          // 30,720,000 B
    float*    el       = (float*)   (ws + 30720000);   //    960,000 B
    float*    er       = (float*)   (ws + 31680000);   //    960,000 B
    float*    ee_table = (float*)   (ws + 32640000);   //        256 B
    unsigned* nmax     = (unsigned*)(ws + 32640256);   //    960,000 B  (zeroed)
    float*    denom    = (float*)   (ws + 33600256);   //    960,000 B  (zeroed)
    int*      counts   = (int*)     (ws + 34560256);   //    120,000 B  (zeroed)
    int*      offsets  = (int*)     (ws + 34680256);   //    120,000 B
    int*      cursor   = (int*)     (ws + 34800256);   //    120,000 B
    int*      sorted   = (int*)     (ws + 34920256);   //  1,920,000 B

    float* rst  = (float*)d_out;                        // [30000,8,32]
    float* aOut = rst + (size_t)N_NODES * HD;           // [480000,8] (also logits scratch)

    // zero the atomic regions (nmax | denom | counts are contiguous)
    hipMemsetAsync(ws + 32640256, 0, 2040000, stream);

    precompute_ee<<<1, 512, 0, stream>>>(edge_emb, W1, b1, W2, b2, attn_e, ee_table);
    gemm_fc<<<dim3((N_NODES + BM - 1) / BM, HD / BN), 256, 0, stream>>>(feat, fc_W, feat_src);
    el_er_kernel<<<(N_NODES * N_HEADS + 255) / 256, 256, 0, stream>>>(feat_src, attn_l, attn_r, el, er);
    logits_kernel<<<(N_EDGES * N_HEADS + 255) / 256, 256, 0, stream>>>(
        src, dst, e_feat, el, er, ee_table, w_r, aOut, nmax, counts);
    exp_kernel<<<(N_EDGES * N_HEADS + 255) / 256, 256, 0, stream>>>(dst, nmax, aOut, denom);
    scan_kernel<<<1, 1024, 0, stream>>>(counts, offsets, cursor);
    norm_kernel<<<(N_EDGES * N_HEADS + 255) / 256, 256, 0, stream>>>(dst, denom, aOut);
    scatter_kernel<<<(N_EDGES + 255) / 256, 256, 0, stream>>>(dst, cursor, sorted);
    aggregate_kernel<<<(N_NODES + 3) / 4, 256, 0, stream>>>(
        offsets, counts, sorted, src, feat_src, aOut, rst);
}

// Round 3
// 369.441 us; speedup vs baseline: 1.4275x; 1.4275x over previous
//
#include <hip/hip_runtime.h>
#include <math.h>

#define N_NODES 30000
#define N_EDGES 480000
#define IN_FEATS 256
#define N_HEADS 8
#define OUT_FEATS 32
#define EDGE_FEATS 64
#define NUM_ETYPES 8
#define NEG_SLOPE 0.2f
#define HD 256  // N_HEADS*OUT_FEATS

typedef __bf16 bf16_t;
typedef bf16_t bf16x8 __attribute__((ext_vector_type(8)));
typedef float f32x4 __attribute__((ext_vector_type(4)));

__device__ __forceinline__ unsigned short f2bf(float f) {
    unsigned u = __float_as_uint(f);
    u += 0x7fffu + ((u >> 16) & 1u);   // round-to-nearest-even
    return (unsigned short)(u >> 16);
}
__device__ __forceinline__ float bf2f(unsigned short s) {
    return __uint_as_float(((unsigned)s) << 16);
}

__device__ __forceinline__ void gload_lds16(const void* g, void* l) {
    __builtin_amdgcn_global_load_lds(
        (const __attribute__((address_space(1))) unsigned int*)g,
        (__attribute__((address_space(3))) unsigned int*)l, 16, 0, 0);
}

// ---------------------------------------------------------------------------
// Kernel 1: edge-type MLP collapsed to 8x8 table ee[type][head] (1 block).
// ---------------------------------------------------------------------------
__global__ void precompute_ee(const float* __restrict__ edge_emb,
                              const float* __restrict__ W1, const float* __restrict__ b1,
                              const float* __restrict__ W2, const float* __restrict__ b2,
                              const float* __restrict__ attn_e,
                              float* __restrict__ ee_table) {
    __shared__ float h1[NUM_ETYPES][2 * EDGE_FEATS];
    __shared__ float h2[NUM_ETYPES][N_HEADS * EDGE_FEATS];
    const int tid = threadIdx.x;          // 512 threads
    const int t = tid >> 6;
    const int j = tid & 63;
    #pragma unroll
    for (int rr = 0; rr < 2; rr++) {
        int row = j + rr * 64;
        float s = b1[row];
        for (int k = 0; k < EDGE_FEATS; k++)
            s = fmaf(W1[row * EDGE_FEATS + k], edge_emb[t * EDGE_FEATS + k], s);
        h1[t][row] = fmaxf(s, 0.f);
    }
    __syncthreads();
    #pragma unroll
    for (int rr = 0; rr < 8; rr++) {
        int row = j * 8 + rr;
        float s = b2[row];
        for (int k = 0; k < 2 * EDGE_FEATS; k++)
            s = fmaf(W2[row * 2 * EDGE_FEATS + k], h1[t][k], s);
        h2[t][row] = s;
    }
    __syncthreads();
    if (j < N_HEADS) {
        float s = 0.f;
        for (int f = 0; f < EDGE_FEATS; f++)
            s = fmaf(h2[t][j * EDGE_FEATS + f], attn_e[j * EDGE_FEATS + f], s);
        ee_table[t * N_HEADS + j] = s;
    }
}

// ---------------------------------------------------------------------------
// Kernel 2: fp32 -> bf16 conversion (feat and fc_W), grid-stride, float4 wide.
// ---------------------------------------------------------------------------
__global__ void cvt_kernel(const float* __restrict__ feat, const float* __restrict__ fcW,
                           unsigned short* __restrict__ featb, unsigned short* __restrict__ fcWb) {
    const int n1 = N_NODES * IN_FEATS / 4;      // 1,920,000 float4 groups
    const int n2 = IN_FEATS * HD / 4;           // 16,384
    int i = blockIdx.x * blockDim.x + threadIdx.x;
    const int stride = gridDim.x * blockDim.x;
    for (; i < n1 + n2; i += stride) {
        float4 v = (i < n1) ? ((const float4*)feat)[i] : ((const float4*)fcW)[i - n1];
        ushort4 o;
        o.x = f2bf(v.x); o.y = f2bf(v.y); o.z = f2bf(v.z); o.w = f2bf(v.w);
        if (i < n1) ((ushort4*)featb)[i] = o;
        else        ((ushort4*)fcWb)[i - n1] = o;
    }
}

// ---------------------------------------------------------------------------
// Kernel 3: bf16 MFMA GEMM  C = feat @ fc_W^T  -> bf16 feat_src [30000][256]
// A [M][256] bf16 row-major, B = fc_W [256][256] bf16 row-major (= B^T ideal).
// 128x64 tile, BK=64, 4 waves (2x2), global_load_lds w/ pre-swizzled source.
// ---------------------------------------------------------------------------
#define GBM 128
#define GBN 64
#define GBK 64
__global__ __launch_bounds__(256) void gemm_bf16(const unsigned short* __restrict__ A,
                                                 const unsigned short* __restrict__ B,
                                                 unsigned short* __restrict__ Cb) {
    __shared__ __align__(16) unsigned char As[GBM * GBK * 2];  // 16 KiB, XOR-swizzled rows
    __shared__ __align__(16) unsigned char Bs[GBN * GBK * 2];  //  8 KiB
    const int tid = threadIdx.x;
    const int lane = tid & 63;
    const int wid = tid >> 6;
    const int wr = wid >> 1, wc = wid & 1;
    const int row0 = blockIdx.x * GBM;
    const int col0 = blockIdx.y * GBN;

    f32x4 acc[4][2] = {};

    for (int k0 = 0; k0 < IN_FEATS; k0 += GBK) {
        __syncthreads();
        // stage A: 4 wave-issues x 1KB. LDS linear [row][chunk]; source chunk
        // pre-swizzled (c ^ (row&7)) so swizzled layout lands via linear DMA.
        #pragma unroll
        for (int i = 0; i < 4; i++) {
            int loff = wid * 4096 + i * 1024;          // wave-uniform LDS base
            int row = (loff >> 7) + (lane >> 3);
            int c = lane & 7;
            int gr = row0 + row; if (gr > N_NODES - 1) gr = N_NODES - 1;
            int gc = k0 + ((c ^ (row & 7)) << 3);
            gload_lds16(A + (size_t)gr * IN_FEATS + gc, As + loff + lane * 16);
        }
        // stage B: 2 wave-issues x 1KB
        #pragma unroll
        for (int i = 0; i < 2; i++) {
            int loff = wid * 2048 + i * 1024;
            int row = (loff >> 7) + (lane >> 3);
            int c = lane & 7;
            int gc = k0 + ((c ^ (row & 7)) << 3);
            gload_lds16(B + (size_t)(col0 + row) * IN_FEATS + gc, Bs + loff + lane * 16);
        }
        asm volatile("s_waitcnt vmcnt(0)" ::: "memory");
        __syncthreads();
        #pragma unroll
        for (int kk = 0; kk < 2; kk++) {
            bf16x8 af[4], bfr[2];
            const int g = kk * 4 + (lane >> 4);        // 16B k-chunk index
            #pragma unroll
            for (int fm = 0; fm < 4; fm++) {
                int row = wr * 64 + fm * 16 + (lane & 15);
                af[fm] = *(const bf16x8*)(As + row * 128 + ((g ^ (row & 7)) << 4));
            }
            #pragma unroll
            for (int fn = 0; fn < 2; fn++) {
                int row = wc * 32 + fn * 16 + (lane & 15);
                bfr[fn] = *(const bf16x8*)(Bs + row * 128 + ((g ^ (row & 7)) << 4));
            }
            #pragma unroll
            for (int fm = 0; fm < 4; fm++)
                #pragma unroll
                for (int fn = 0; fn < 2; fn++)
                    acc[fm][fn] = __builtin_amdgcn_mfma_f32_16x16x32_bf16(
                        af[fm], bfr[fn], acc[fm][fn], 0, 0, 0);
        }
    }
    // epilogue: C/D map col=lane&15, row=(lane>>4)*4+r  [m89-verified]
    #pragma unroll
    for (int fm = 0; fm < 4; fm++) {
        #pragma unroll
        for (int r = 0; r < 4; r++) {
            int row = row0 + wr * 64 + fm * 16 + (lane >> 4) * 4 + r;
            if (row < N_NODES) {
                #pragma unroll
                for (int fn = 0; fn < 2; fn++) {
                    int col = col0 + wc * 32 + fn * 16 + (lane & 15);
                    Cb[(size_t)row * HD + col] = f2bf(acc[fm][fn][r]);
                }
            }
        }
    }
}

// ---------------------------------------------------------------------------
// Kernel 4: el/er from bf16 feat_src
// ---------------------------------------------------------------------------
__global__ void el_er_kernel(const unsigned short* __restrict__ fsb,
                             const float* __restrict__ attn_l,
                             const float* __restrict__ attn_r,
                             float* __restrict__ el, float* __restrict__ er) {
    int i = blockIdx.x * blockDim.x + threadIdx.x;   // n*8+h
    if (i >= N_NODES * N_HEADS) return;
    int h = i & 7;
    const ushort4* fs = (const ushort4*)(fsb + (size_t)i * OUT_FEATS);
    const float4* al = (const float4*)(attn_l + h * OUT_FEATS);
    const float4* ar = (const float4*)(attn_r + h * OUT_FEATS);
    float sl = 0.f, sr = 0.f;
    #pragma unroll
    for (int q = 0; q < 8; q++) {
        ushort4 u = fs[q];
        float4 a = al[q], b = ar[q];
        float x0 = bf2f(u.x), x1 = bf2f(u.y), x2 = bf2f(u.z), x3 = bf2f(u.w);
        sl += x0 * a.x + x1 * a.y + x2 * a.z + x3 * a.w;
        sr += x0 * b.x + x1 * b.y + x2 * b.z + x3 * b.w;
    }
    el[i] = sl; er[i] = sr;
}

// ---------------------------------------------------------------------------
// Kernel 5: histogram of dst
// ---------------------------------------------------------------------------
__global__ void hist_kernel(const int* __restrict__ dst, int* __restrict__ counts) {
    int e = blockIdx.x * blockDim.x + threadIdx.x;
    if (e < N_EDGES) atomicAdd(&counts[dst[e]], 1);
}

// ---------------------------------------------------------------------------
// Kernel 6: exclusive scan of counts -> offsets (+ cursor). One block.
// ---------------------------------------------------------------------------
__global__ void scan_kernel(const int* __restrict__ counts, int* __restrict__ offsets,
                            int* __restrict__ cursor) {
    __shared__ int sums[1024];
    const int T = 1024;
    const int per = (N_NODES + T - 1) / T;
    int t = threadIdx.x;
    int beg = t * per;
    int end = beg + per; if (end > N_NODES) end = N_NODES;
    int s = 0;
    for (int i = beg; i < end; i++) s += counts[i];
    sums[t] = s;
    __syncthreads();
    for (int off = 1; off < T; off <<= 1) {
        int v = (t >= off) ? sums[t - off] : 0;
        __syncthreads();
        sums[t] += v;
        __syncthreads();
    }
    int run = sums[t] - s;
    for (int i = beg; i < end; i++) {
        offsets[i] = run; cursor[i] = run;
        run += counts[i];
    }
}

// Kernel 7: scatter edge ids into CSR order
__global__ void scatter_kernel(const int* __restrict__ dst, int* __restrict__ cursor,
                               int* __restrict__ sorted_eid) {
    int e = blockIdx.x * blockDim.x + threadIdx.x;
    if (e >= N_EDGES) return;
    int pos = atomicAdd(&cursor[dst[e]], 1);
    sorted_eid[pos] = e;
}

// ---------------------------------------------------------------------------
// Kernel 8: fused per-node softmax + aggregation. One wave per dst node.
// Lanes (e_local = lane>>3, h = lane&7) for softmax; (head=lane>>3, d=(lane&7)*4)
// i.e. lane owns 4 consecutive d's of one head for aggregation.
// ---------------------------------------------------------------------------
__global__ __launch_bounds__(256) void node_fused(
    const int* __restrict__ offsets, const int* __restrict__ counts,
    const int* __restrict__ sorted, const int* __restrict__ src,
    const int* __restrict__ etype,
    const float* __restrict__ el, const float* __restrict__ er,
    const float* __restrict__ ee_tab, const float* __restrict__ w_r,
    const unsigned short* __restrict__ fsb,
    float* __restrict__ rst, float* __restrict__ aOut) {
    __shared__ float eeS[64];
    __shared__ float wrS[8];
    __shared__ float lgS[4][64][8];   // per-wave logit cache, then 'a' staging
    __shared__ int   sS[4][8];
    if (threadIdx.x < 64) eeS[threadIdx.x] = ee_tab[threadIdx.x];
    if (threadIdx.x < 8)  wrS[threadIdx.x] = w_r[threadIdx.x];
    __syncthreads();
    const int wv = threadIdx.x >> 6, lane = threadIdx.x & 63;
    const int node = blockIdx.x * 4 + wv;
    if (node >= N_NODES) return;
    const int beg = offsets[node], cnt = counts[node];
    const int e_l = lane >> 3, h = lane & 7;
    const float er_v = er[node * 8 + h];
    const int nch = (cnt + 7) >> 3;

    // pass A: logits -> LDS cache, per-lane max
    float m = -1e30f;
    for (int ch = 0; ch < nch; ch++) {
        int idx = ch * 8 + e_l;
        float lg = -1e30f;
        if (idx < cnt) {
            int eid = sorted[beg + idx];
            int s = src[eid], t = etype[eid];
            float x = el[s * 8 + h] + er_v + eeS[t * 8 + h];
            x = (x > 0.f) ? x : NEG_SLOPE * x;
            lg = x * wrS[t];
        }
        if (idx < 64) lgS[wv][idx][h] = lg;
        m = fmaxf(m, lg);
    }
    m = fmaxf(m, __shfl_xor(m, 8));
    m = fmaxf(m, __shfl_xor(m, 16));
    m = fmaxf(m, __shfl_xor(m, 32));

    // pass B: denom
    float sum = 0.f;
    for (int ch = 0; ch < nch; ch++) {
        int idx = ch * 8 + e_l;
        if (idx < cnt) {
            float lg;
            if (idx < 64) lg = lgS[wv][idx][h];
            else {
                int eid = sorted[beg + idx];
                int s = src[eid], t = etype[eid];
                float x = el[s * 8 + h] + er_v + eeS[t * 8 + h];
                x = (x > 0.f) ? x : NEG_SLOPE * x;
                lg = x * wrS[t];
            }
            sum += __expf(lg - m);
        }
    }
    sum += __shfl_xor(sum, 8);
    sum += __shfl_xor(sum, 16);
    sum += __shfl_xor(sum, 32);
    const float inv = 1.f / sum;   // cnt==0 -> unused

    // pass C: a = ex*inv -> write + stage; aggregate chunk
    float acc0 = 0.f, acc1 = 0.f, acc2 = 0.f, acc3 = 0.f;
    const int hq = lane >> 3;       // aggregation head (lane*4)>>5
    for (int ch = 0; ch < nch; ch++) {
        int idx = ch * 8 + e_l;
        float a = 0.f; int s = 0;
        if (idx < cnt) {
            int eid = sorted[beg + idx];
            s = src[eid];
            float lg;
            if (idx < 64) lg = lgS[wv][idx][h];
            else {
                int t = etype[eid];
                float x = el[s * 8 + h] + er_v + eeS[t * 8 + h];
                x = (x > 0.f) ? x : NEG_SLOPE * x;
                lg = x * wrS[t];
            }
            a = __expf(lg - m) * inv;
            aOut[(size_t)eid * 8 + h] = a;
        }
        lgS[wv][idx & 63][h] = a;           // own slot: read-before-write above
        if (h == 0) sS[wv][e_l] = s;
        int lim = cnt - ch * 8; if (lim > 8) lim = 8;
        for (int j = 0; j < lim; j++) {
            int sj = sS[wv][j];
            float av = lgS[wv][(ch * 8 + j) & 63][hq];
            ushort4 u = *(const ushort4*)(fsb + (size_t)sj * HD + lane * 4);
            acc0 = fmaf(av, bf2f(u.x), acc0);
            acc1 = fmaf(av, bf2f(u.y), acc1);
            acc2 = fmaf(av, bf2f(u.z), acc2);
            acc3 = fmaf(av, bf2f(u.w), acc3);
        }
    }
    *(float4*)(rst + (size_t)node * HD + lane * 4) = make_float4(acc0, acc1, acc2, acc3);
}

// ---------------------------------------------------------------------------
extern "C" void kernel_launch(void* const* d_in, const int* in_sizes, int n_in,
                              void* d_out, int out_size, void* d_ws, size_t ws_size,
                              hipStream_t stream) {
    const float* feat     = (const float*)d_in[0];
    const int*   e_feat   = (const int*)  d_in[1];
    const int*   src      = (const int*)  d_in[2];
    const int*   dst      = (const int*)  d_in[3];
    const float* fc_W     = (const float*)d_in[4];
    const float* edge_emb = (const float*)d_in[5];
    const float* w_r      = (const float*)d_in[6];
    const float* W1       = (const float*)d_in[7];
    const float* b1       = (const float*)d_in[8];
    const float* W2       = (const float*)d_in[9];
    const float* b2       = (const float*)d_in[10];
    const float* attn_l   = (const float*)d_in[11];
    const float* attn_r   = (const float*)d_in[12];
    const float* attn_e   = (const float*)d_in[13];

    char* ws = (char*)d_ws;
    unsigned short* featb  = (unsigned short*)(ws + 0);           // 15,360,000
    unsigned short* fsb    = (unsigned short*)(ws + 15360000);    // 15,360,000
    float*          el     = (float*)(ws + 30720000);             //    960,000
    float*          er     = (float*)(ws + 31680000);             //    960,000
    unsigned short* fcWb   = (unsigned short*)(ws + 32640000);    //    131,072
    float*          ee_tab = (float*)(ws + 32771072);             //        256
    int*            counts = (int*)(ws + 32771328);               //    120,000 (zeroed)
    int*            offs   = (int*)(ws + 32891328);               //    120,000
    int*            cursor = (int*)(ws + 33011328);               //    120,000
    int*            sorted = (int*)(ws + 33131328);               //  1,920,000

    float* rst  = (float*)d_out;                     // [30000,8,32]
    float* aOut = rst + (size_t)N_NODES * HD;        // [480000,8]

    hipMemsetAsync(counts, 0, 120000, stream);
    precompute_ee<<<1, 512, 0, stream>>>(edge_emb, W1, b1, W2, b2, attn_e, ee_tab);
    cvt_kernel<<<2048, 256, 0, stream>>>(feat, fc_W, featb, fcWb);
    hist_kernel<<<(N_EDGES + 255) / 256, 256, 0, stream>>>(dst, counts);
    scan_kernel<<<1, 1024, 0, stream>>>(counts, offs, cursor);
    scatter_kernel<<<(N_EDGES + 255) / 256, 256, 0, stream>>>(dst, cursor, sorted);
    gemm_bf16<<<dim3((N_NODES + GBM - 1) / GBM, HD / GBN), 256, 0, stream>>>(featb, fcWb, fsb);
    el_er_kernel<<<(N_NODES * N_HEADS + 255) / 256, 256, 0, stream>>>(fsb, attn_l, attn_r, el, er);
    node_fused<<<(N_NODES + 3) / 4, 256, 0, stream>>>(
        offs, counts, sorted, src, e_feat, el, er, ee_tab, w_r, fsb, rst, aOut);
}

// Round 4
// 308.438 us; speedup vs baseline: 1.7098x; 1.1978x over previous
//
#include <hip/hip_runtime.h>
#include <math.h>

#define N_NODES 30000
#define N_EDGES 480000
#define IN_FEATS 256
#define N_HEADS 8
#define OUT_FEATS 32
#define EDGE_FEATS 64
#define NUM_ETYPES 8
#define NEG_SLOPE 0.2f
#define HD 256  // N_HEADS*OUT_FEATS

typedef __bf16 bf16_t;
typedef bf16_t bf16x8 __attribute__((ext_vector_type(8)));
typedef float f32x4 __attribute__((ext_vector_type(4)));

__device__ __forceinline__ unsigned short f2bf(float f) {
    unsigned u = __float_as_uint(f);
    u += 0x7fffu + ((u >> 16) & 1u);   // round-to-nearest-even
    return (unsigned short)(u >> 16);
}
__device__ __forceinline__ float bf2f(unsigned short s) {
    return __uint_as_float(((unsigned)s) << 16);
}

__device__ __forceinline__ void gload_lds16(const void* g, void* l) {
    __builtin_amdgcn_global_load_lds(
        (const __attribute__((address_space(1))) unsigned int*)g,
        (__attribute__((address_space(3))) unsigned int*)l, 16, 0, 0);
}

// ---------------------------------------------------------------------------
// Kernel 1a: ee precompute, stage 1 (parallel, factorized).
//   tid 0..1023   : h1[t][r] = relu(b1[r] + dot(W1[r,:], edge_emb[t,:]))
//   tid 1024..2047: M[h][k]  = sum_f attn_e[h,f] * W2[h*64+f, k]   (coalesced)
// ---------------------------------------------------------------------------
__global__ void ee_mid(const float* __restrict__ edge_emb,
                       const float* __restrict__ W1, const float* __restrict__ b1,
                       const float* __restrict__ W2, const float* __restrict__ attn_e,
                       float* __restrict__ h1_ws, float* __restrict__ M_ws) {
    int i = blockIdx.x * blockDim.x + threadIdx.x;   // 0..2047
    if (i < 1024) {
        int t = i >> 7, r = i & 127;
        const float4* Wv = (const float4*)(W1 + (size_t)r * EDGE_FEATS);
        const float4* Ev = (const float4*)(edge_emb + (size_t)t * EDGE_FEATS);
        float s = b1[r];
        #pragma unroll
        for (int q = 0; q < 16; q++) {
            float4 w = Wv[q], e = Ev[q];
            s += w.x * e.x + w.y * e.y + w.z * e.z + w.w * e.w;
        }
        h1_ws[i] = fmaxf(s, 0.f);
    } else {
        int m = i - 1024;
        int h = m >> 7, k = m & 127;     // lanes consecutive in k -> coalesced W2
        float s = 0.f;
        #pragma unroll 8
        for (int f = 0; f < EDGE_FEATS; f++)
            s = fmaf(attn_e[h * EDGE_FEATS + f],
                     W2[(size_t)(h * EDGE_FEATS + f) * (2 * EDGE_FEATS) + k], s);
        M_ws[m] = s;
    }
}

// Kernel 1b: ee[t][h] = c[h] + dot(M[h,:], h1[t,:])   (64 outputs, 1 block)
__global__ void ee_fin(const float* __restrict__ h1_ws, const float* __restrict__ M_ws,
                       const float* __restrict__ attn_e, const float* __restrict__ b2,
                       float* __restrict__ ee_tab) {
    int j = threadIdx.x;                 // 64 threads
    if (j >= 64) return;
    int t = j >> 3, h = j & 7;
    float s = 0.f;
    for (int f = 0; f < EDGE_FEATS; f++)
        s = fmaf(attn_e[h * EDGE_FEATS + f], b2[h * EDGE_FEATS + f], s);
    for (int k = 0; k < 2 * EDGE_FEATS; k++)
        s = fmaf(M_ws[h * 128 + k], h1_ws[t * 128 + k], s);
    ee_tab[j] = s;
}

// ---------------------------------------------------------------------------
// Kernel 2: fp32 -> bf16 conversion (feat and fc_W), grid-stride, float4 wide.
// ---------------------------------------------------------------------------
__global__ void cvt_kernel(const float* __restrict__ feat, const float* __restrict__ fcW,
                           unsigned short* __restrict__ featb, unsigned short* __restrict__ fcWb) {
    const int n1 = N_NODES * IN_FEATS / 4;      // 1,920,000 float4 groups
    const int n2 = IN_FEATS * HD / 4;           // 16,384
    int i = blockIdx.x * blockDim.x + threadIdx.x;
    const int stride = gridDim.x * blockDim.x;
    for (; i < n1 + n2; i += stride) {
        float4 v = (i < n1) ? ((const float4*)feat)[i] : ((const float4*)fcW)[i - n1];
        ushort4 o;
        o.x = f2bf(v.x); o.y = f2bf(v.y); o.z = f2bf(v.z); o.w = f2bf(v.w);
        if (i < n1) ((ushort4*)featb)[i] = o;
        else        ((ushort4*)fcWb)[i - n1] = o;
    }
}

// ---------------------------------------------------------------------------
// Kernel 3: bf16 MFMA GEMM  C = feat @ fc_W^T  -> bf16 feat_src [30000][256]
// 128x64 tile, BK=64, 4 waves (2x2), global_load_lds w/ pre-swizzled source.
// ---------------------------------------------------------------------------
#define GBM 128
#define GBN 64
#define GBK 64
__global__ __launch_bounds__(256) void gemm_bf16(const unsigned short* __restrict__ A,
                                                 const unsigned short* __restrict__ B,
                                                 unsigned short* __restrict__ Cb) {
    __shared__ __align__(16) unsigned char As[GBM * GBK * 2];  // 16 KiB, XOR-swizzled rows
    __shared__ __align__(16) unsigned char Bs[GBN * GBK * 2];  //  8 KiB
    const int tid = threadIdx.x;
    const int lane = tid & 63;
    const int wid = tid >> 6;
    const int wr = wid >> 1, wc = wid & 1;
    const int row0 = blockIdx.x * GBM;
    const int col0 = blockIdx.y * GBN;

    f32x4 acc[4][2] = {};

    for (int k0 = 0; k0 < IN_FEATS; k0 += GBK) {
        __syncthreads();
        #pragma unroll
        for (int i = 0; i < 4; i++) {
            int loff = wid * 4096 + i * 1024;          // wave-uniform LDS base
            int row = (loff >> 7) + (lane >> 3);
            int c = lane & 7;
            int gr = row0 + row; if (gr > N_NODES - 1) gr = N_NODES - 1;
            int gc = k0 + ((c ^ (row & 7)) << 3);
            gload_lds16(A + (size_t)gr * IN_FEATS + gc, As + loff + lane * 16);
        }
        #pragma unroll
        for (int i = 0; i < 2; i++) {
            int loff = wid * 2048 + i * 1024;
            int row = (loff >> 7) + (lane >> 3);
            int c = lane & 7;
            int gc = k0 + ((c ^ (row & 7)) << 3);
            gload_lds16(B + (size_t)(col0 + row) * IN_FEATS + gc, Bs + loff + lane * 16);
        }
        asm volatile("s_waitcnt vmcnt(0)" ::: "memory");
        __syncthreads();
        #pragma unroll
        for (int kk = 0; kk < 2; kk++) {
            bf16x8 af[4], bfr[2];
            const int g = kk * 4 + (lane >> 4);        // 16B k-chunk index
            #pragma unroll
            for (int fm = 0; fm < 4; fm++) {
                int row = wr * 64 + fm * 16 + (lane & 15);
                af[fm] = *(const bf16x8*)(As + row * 128 + ((g ^ (row & 7)) << 4));
            }
            #pragma unroll
            for (int fn = 0; fn < 2; fn++) {
                int row = wc * 32 + fn * 16 + (lane & 15);
                bfr[fn] = *(const bf16x8*)(Bs + row * 128 + ((g ^ (row & 7)) << 4));
            }
            #pragma unroll
            for (int fm = 0; fm < 4; fm++)
                #pragma unroll
                for (int fn = 0; fn < 2; fn++)
                    acc[fm][fn] = __builtin_amdgcn_mfma_f32_16x16x32_bf16(
                        af[fm], bfr[fn], acc[fm][fn], 0, 0, 0);
        }
    }
    // epilogue: C/D map col=lane&15, row=(lane>>4)*4+r  [m89-verified]
    #pragma unroll
    for (int fm = 0; fm < 4; fm++) {
        #pragma unroll
        for (int r = 0; r < 4; r++) {
            int row = row0 + wr * 64 + fm * 16 + (lane >> 4) * 4 + r;
            if (row < N_NODES) {
                #pragma unroll
                for (int fn = 0; fn < 2; fn++) {
                    int col = col0 + wc * 32 + fn * 16 + (lane & 15);
                    Cb[(size_t)row * HD + col] = f2bf(acc[fm][fn][r]);
                }
            }
        }
    }
}

// ---------------------------------------------------------------------------
// Kernel 4: el/er from bf16 feat_src
// ---------------------------------------------------------------------------
__global__ void el_er_kernel(const unsigned short* __restrict__ fsb,
                             const float* __restrict__ attn_l,
                             const float* __restrict__ attn_r,
                             float* __restrict__ el, float* __restrict__ er) {
    int i = blockIdx.x * blockDim.x + threadIdx.x;   // n*8+h
    if (i >= N_NODES * N_HEADS) return;
    int h = i & 7;
    const ushort4* fs = (const ushort4*)(fsb + (size_t)i * OUT_FEATS);
    const float4* al = (const float4*)(attn_l + h * OUT_FEATS);
    const float4* ar = (const float4*)(attn_r + h * OUT_FEATS);
    float sl = 0.f, sr = 0.f;
    #pragma unroll
    for (int q = 0; q < 8; q++) {
        ushort4 u = fs[q];
        float4 a = al[q], b = ar[q];
        float x0 = bf2f(u.x), x1 = bf2f(u.y), x2 = bf2f(u.z), x3 = bf2f(u.w);
        sl += x0 * a.x + x1 * a.y + x2 * a.z + x3 * a.w;
        sr += x0 * b.x + x1 * b.y + x2 * b.z + x3 * b.w;
    }
    el[i] = sl; er[i] = sr;
}

// ---------------------------------------------------------------------------
// Kernel 5: histogram of dst
// ---------------------------------------------------------------------------
__global__ void hist_kernel(const int* __restrict__ dst, int* __restrict__ counts) {
    int e = blockIdx.x * blockDim.x + threadIdx.x;
    if (e < N_EDGES) atomicAdd(&counts[dst[e]], 1);
}

// ---------------------------------------------------------------------------
// Kernel 6: exclusive scan of counts -> offsets (+ cursor). One block.
// ---------------------------------------------------------------------------
__global__ void scan_kernel(const int* __restrict__ counts, int* __restrict__ offsets,
                            int* __restrict__ cursor) {
    __shared__ int sums[1024];
    const int T = 1024;
    const int per = (N_NODES + T - 1) / T;
    int t = threadIdx.x;
    int beg = t * per;
    int end = beg + per; if (end > N_NODES) end = N_NODES;
    int s = 0;
    for (int i = beg; i < end; i++) s += counts[i];
    sums[t] = s;
    __syncthreads();
    for (int off = 1; off < T; off <<= 1) {
        int v = (t >= off) ? sums[t - off] : 0;
        __syncthreads();
        sums[t] += v;
        __syncthreads();
    }
    int run = sums[t] - s;
    for (int i = beg; i < end; i++) {
        offsets[i] = run; cursor[i] = run;
        run += counts[i];
    }
}

// Kernel 7: scatter edge ids into CSR order
__global__ void scatter_kernel(const int* __restrict__ dst, int* __restrict__ cursor,
                               int* __restrict__ sorted_eid) {
    int e = blockIdx.x * blockDim.x + threadIdx.x;
    if (e >= N_EDGES) return;
    int pos = atomicAdd(&cursor[dst[e]], 1);
    sorted_eid[pos] = e;
}

// ---------------------------------------------------------------------------
// Kernel 8: fused per-node softmax + aggregation. One wave per dst node.
// Lanes (e_local = lane>>3, h = lane&7) for softmax; (head=lane>>3, d=(lane&7)*4)
// ---------------------------------------------------------------------------
__global__ __launch_bounds__(256) void node_fused(
    const int* __restrict__ offsets, const int* __restrict__ counts,
    const int* __restrict__ sorted, const int* __restrict__ src,
    const int* __restrict__ etype,
    const float* __restrict__ el, const float* __restrict__ er,
    const float* __restrict__ ee_tab, const float* __restrict__ w_r,
    const unsigned short* __restrict__ fsb,
    float* __restrict__ rst, float* __restrict__ aOut) {
    __shared__ float eeS[64];
    __shared__ float wrS[8];
    __shared__ float lgS[4][64][8];   // per-wave logit cache, then 'a' staging
    __shared__ int   sS[4][8];
    if (threadIdx.x < 64) eeS[threadIdx.x] = ee_tab[threadIdx.x];
    if (threadIdx.x < 8)  wrS[threadIdx.x] = w_r[threadIdx.x];
    __syncthreads();
    const int wv = threadIdx.x >> 6, lane = threadIdx.x & 63;
    const int node = blockIdx.x * 4 + wv;
    if (node >= N_NODES) return;
    const int beg = offsets[node], cnt = counts[node];
    const int e_l = lane >> 3, h = lane & 7;
    const float er_v = er[node * 8 + h];
    const int nch = (cnt + 7) >> 3;

    // pass A: logits -> LDS cache, per-lane max
    float m = -1e30f;
    for (int ch = 0; ch < nch; ch++) {
        int idx = ch * 8 + e_l;
        float lg = -1e30f;
        if (idx < cnt) {
            int eid = sorted[beg + idx];
            int s = src[eid], t = etype[eid];
            float x = el[s * 8 + h] + er_v + eeS[t * 8 + h];
            x = (x > 0.f) ? x : NEG_SLOPE * x;
            lg = x * wrS[t];
        }
        if (idx < 64) lgS[wv][idx][h] = lg;
        m = fmaxf(m, lg);
    }
    m = fmaxf(m, __shfl_xor(m, 8));
    m = fmaxf(m, __shfl_xor(m, 16));
    m = fmaxf(m, __shfl_xor(m, 32));

    // pass B: denom
    float sum = 0.f;
    for (int ch = 0; ch < nch; ch++) {
        int idx = ch * 8 + e_l;
        if (idx < cnt) {
            float lg;
            if (idx < 64) lg = lgS[wv][idx][h];
            else {
                int eid = sorted[beg + idx];
                int s = src[eid], t = etype[eid];
                float x = el[s * 8 + h] + er_v + eeS[t * 8 + h];
                x = (x > 0.f) ? x : NEG_SLOPE * x;
                lg = x * wrS[t];
            }
            sum += __expf(lg - m);
        }
    }
    sum += __shfl_xor(sum, 8);
    sum += __shfl_xor(sum, 16);
    sum += __shfl_xor(sum, 32);
    const float inv = 1.f / sum;   // cnt==0 -> unused

    // pass C: a = ex*inv -> write + stage; aggregate chunk
    float acc0 = 0.f, acc1 = 0.f, acc2 = 0.f, acc3 = 0.f;
    const int hq = lane >> 3;       // aggregation head
    for (int ch = 0; ch < nch; ch++) {
        int idx = ch * 8 + e_l;
        float a = 0.f; int s = 0;
        if (idx < cnt) {
            int eid = sorted[beg + idx];
            s = src[eid];
            float lg;
            if (idx < 64) lg = lgS[wv][idx][h];
            else {
                int t = etype[eid];
                float x = el[s * 8 + h] + er_v + eeS[t * 8 + h];
                x = (x > 0.f) ? x : NEG_SLOPE * x;
                lg = x * wrS[t];
            }
            a = __expf(lg - m) * inv;
            aOut[(size_t)eid * 8 + h] = a;
        }
        lgS[wv][idx & 63][h] = a;           // own slot: read-before-write above
        if (h == 0) sS[wv][e_l] = s;
        int lim = cnt - ch * 8; if (lim > 8) lim = 8;
        for (int j = 0; j < lim; j++) {
            int sj = sS[wv][j];
            float av = lgS[wv][(ch * 8 + j) & 63][hq];
            ushort4 u = *(const ushort4*)(fsb + (size_t)sj * HD + lane * 4);
            acc0 = fmaf(av, bf2f(u.x), acc0);
            acc1 = fmaf(av, bf2f(u.y), acc1);
            acc2 = fmaf(av, bf2f(u.z), acc2);
            acc3 = fmaf(av, bf2f(u.w), acc3);
        }
    }
    *(float4*)(rst + (size_t)node * HD + lane * 4) = make_float4(acc0, acc1, acc2, acc3);
}

// ---------------------------------------------------------------------------
extern "C" void kernel_launch(void* const* d_in, const int* in_sizes, int n_in,
                              void* d_out, int out_size, void* d_ws, size_t ws_size,
                              hipStream_t stream) {
    const float* feat     = (const float*)d_in[0];
    const int*   e_feat   = (const int*)  d_in[1];
    const int*   src      = (const int*)  d_in[2];
    const int*   dst      = (const int*)  d_in[3];
    const float* fc_W     = (const float*)d_in[4];
    const float* edge_emb = (const float*)d_in[5];
    const float* w_r      = (const float*)d_in[6];
    const float* W1       = (const float*)d_in[7];
    const float* b1       = (const float*)d_in[8];
    const float* W2       = (const float*)d_in[9];
    const float* b2       = (const float*)d_in[10];
    const float* attn_l   = (const float*)d_in[11];
    const float* attn_r   = (const float*)d_in[12];
    const float* attn_e   = (const float*)d_in[13];

    char* ws = (char*)d_ws;
    unsigned short* featb  = (unsigned short*)(ws + 0);           // 15,360,000
    unsigned short* fsb    = (unsigned short*)(ws + 15360000);    // 15,360,000
    float*          el     = (float*)(ws + 30720000);             //    960,000
    float*          er     = (float*)(ws + 31680000);             //    960,000
    unsigned short* fcWb   = (unsigned short*)(ws + 32640000);    //    131,072
    float*          ee_tab = (float*)(ws + 32771072);             //        256
    int*            counts = (int*)(ws + 32771328);               //    120,000 (zeroed)
    int*            offs   = (int*)(ws + 32891328);               //    120,000
    int*            cursor = (int*)(ws + 33011328);               //    120,000
    int*            sorted = (int*)(ws + 33131328);               //  1,920,000
    float*          h1_ws  = (float*)(ws + 35051328);             //      4,096
    float*          M_ws   = (float*)(ws + 35055424);             //      4,096

    float* rst  = (float*)d_out;                     // [30000,8,32]
    float* aOut = rst + (size_t)N_NODES * HD;        // [480000,8]

    hipMemsetAsync(counts, 0, 120000, stream);
    ee_mid<<<8, 256, 0, stream>>>(edge_emb, W1, b1, W2, attn_e, h1_ws, M_ws);
    ee_fin<<<1, 64, 0, stream>>>(h1_ws, M_ws, attn_e, b2, ee_tab);
    cvt_kernel<<<2048, 256, 0, stream>>>(feat, fc_W, featb, fcWb);
    hist_kernel<<<(N_EDGES + 255) / 256, 256, 0, stream>>>(dst, counts);
    scan_kernel<<<1, 1024, 0, stream>>>(counts, offs, cursor);
    scatter_kernel<<<(N_EDGES + 255) / 256, 256, 0, stream>>>(dst, cursor, sorted);
    gemm_bf16<<<dim3((N_NODES + GBM - 1) / GBM, HD / GBN), 256, 0, stream>>>(featb, fcWb, fsb);
    el_er_kernel<<<(N_NODES * N_HEADS + 255) / 256, 256, 0, stream>>>(fsb, attn_l, attn_r, el, er);
    node_fused<<<(N_NODES + 3) / 4, 256, 0, stream>>>(
        offs, counts, sorted, src, e_feat, el, er, ee_tab, w_r, fsb, rst, aOut);
}

// Round 5
// 302.151 us; speedup vs baseline: 1.7454x; 1.0208x over previous
//
#include <hip/hip_runtime.h>
#include <math.h>

#define N_NODES 30000
#define N_EDGES 480000
#define IN_FEATS 256
#define N_HEADS 8
#define OUT_FEATS 32
#define EDGE_FEATS 64
#define NUM_ETYPES 8
#define NEG_SLOPE 0.2f
#define HD 256  // N_HEADS*OUT_FEATS

typedef __bf16 bf16_t;
typedef bf16_t bf16x8 __attribute__((ext_vector_type(8)));
typedef float f32x4 __attribute__((ext_vector_type(4)));
typedef unsigned short ushort8_t __attribute__((ext_vector_type(8)));

__device__ __forceinline__ unsigned short f2bf(float f) {
    unsigned u = __float_as_uint(f);
    u += 0x7fffu + ((u >> 16) & 1u);   // round-to-nearest-even
    return (unsigned short)(u >> 16);
}
__device__ __forceinline__ float bf2f(unsigned short s) {
    return __uint_as_float(((unsigned)s) << 16);
}

__device__ __forceinline__ void gload_lds16(const void* g, void* l) {
    __builtin_amdgcn_global_load_lds(
        (const __attribute__((address_space(1))) unsigned int*)g,
        (__attribute__((address_space(3))) unsigned int*)l, 16, 0, 0);
}

// ---------------------------------------------------------------------------
// Kernel 1a: ee precompute stage 1 (factorized, parallel).
// ---------------------------------------------------------------------------
__global__ void ee_mid(const float* __restrict__ edge_emb,
                       const float* __restrict__ W1, const float* __restrict__ b1,
                       const float* __restrict__ W2, const float* __restrict__ attn_e,
                       float* __restrict__ h1_ws, float* __restrict__ M_ws) {
    int i = blockIdx.x * blockDim.x + threadIdx.x;   // 0..2047
    if (i < 1024) {
        int t = i >> 7, r = i & 127;
        const float4* Wv = (const float4*)(W1 + (size_t)r * EDGE_FEATS);
        const float4* Ev = (const float4*)(edge_emb + (size_t)t * EDGE_FEATS);
        float s = b1[r];
        #pragma unroll
        for (int q = 0; q < 16; q++) {
            float4 w = Wv[q], e = Ev[q];
            s += w.x * e.x + w.y * e.y + w.z * e.z + w.w * e.w;
        }
        h1_ws[i] = fmaxf(s, 0.f);
    } else {
        int m = i - 1024;
        int h = m >> 7, k = m & 127;     // lanes consecutive in k -> coalesced W2
        float s = 0.f;
        #pragma unroll 8
        for (int f = 0; f < EDGE_FEATS; f++)
            s = fmaf(attn_e[h * EDGE_FEATS + f],
                     W2[(size_t)(h * EDGE_FEATS + f) * (2 * EDGE_FEATS) + k], s);
        M_ws[m] = s;
    }
}

// Kernel 1b: ee[t][h] = c[h] + dot(M[h,:], h1[t,:])
__global__ void ee_fin(const float* __restrict__ h1_ws, const float* __restrict__ M_ws,
                       const float* __restrict__ attn_e, const float* __restrict__ b2,
                       float* __restrict__ ee_tab) {
    int j = threadIdx.x;                 // 64 threads
    if (j >= 64) return;
    int t = j >> 3, h = j & 7;
    float s = 0.f;
    for (int f = 0; f < EDGE_FEATS; f++)
        s = fmaf(attn_e[h * EDGE_FEATS + f], b2[h * EDGE_FEATS + f], s);
    for (int k = 0; k < 2 * EDGE_FEATS; k++)
        s = fmaf(M_ws[h * 128 + k], h1_ws[t * 128 + k], s);
    ee_tab[j] = s;
}

// ---------------------------------------------------------------------------
// Kernel 2: fp32->bf16 conversion (feat, fc_W) + dst histogram, fused.
// ---------------------------------------------------------------------------
__global__ void cvt_hist(const float* __restrict__ feat, const float* __restrict__ fcW,
                         const int* __restrict__ dst,
                         unsigned short* __restrict__ featb, unsigned short* __restrict__ fcWb,
                         int* __restrict__ counts) {
    const int n1 = N_NODES * IN_FEATS / 4;      // 1,920,000 float4 groups
    const int n2 = IN_FEATS * HD / 4;           // 16,384
    const int tid0 = blockIdx.x * blockDim.x + threadIdx.x;
    const int stride = gridDim.x * blockDim.x;
    for (int i = tid0; i < n1 + n2; i += stride) {
        float4 v = (i < n1) ? ((const float4*)feat)[i] : ((const float4*)fcW)[i - n1];
        ushort4 o;
        o.x = f2bf(v.x); o.y = f2bf(v.y); o.z = f2bf(v.z); o.w = f2bf(v.w);
        if (i < n1) ((ushort4*)featb)[i] = o;
        else        ((ushort4*)fcWb)[i - n1] = o;
    }
    for (int e = tid0; e < N_EDGES; e += stride)
        atomicAdd(&counts[dst[e]], 1);
}

// ---------------------------------------------------------------------------
// Kernel 3: bf16 MFMA GEMM  C = feat @ fc_W^T  -> bf16 feat_src [30000][256]
// + fused el/er epilogue (each wave owns exactly one head's 32 cols).
// ---------------------------------------------------------------------------
#define GBM 128
#define GBN 64
#define GBK 64
__global__ __launch_bounds__(256) void gemm_bf16(const unsigned short* __restrict__ A,
                                                 const unsigned short* __restrict__ B,
                                                 const float* __restrict__ attn_l,
                                                 const float* __restrict__ attn_r,
                                                 unsigned short* __restrict__ Cb,
                                                 float* __restrict__ el,
                                                 float* __restrict__ er) {
    __shared__ __align__(16) unsigned char As[GBM * GBK * 2];  // 16 KiB, XOR-swizzled rows
    __shared__ __align__(16) unsigned char Bs[GBN * GBK * 2];  //  8 KiB
    const int tid = threadIdx.x;
    const int lane = tid & 63;
    const int wid = tid >> 6;
    const int wr = wid >> 1, wc = wid & 1;
    const int row0 = blockIdx.x * GBM;
    const int col0 = blockIdx.y * GBN;

    f32x4 acc[4][2] = {};

    for (int k0 = 0; k0 < IN_FEATS; k0 += GBK) {
        __syncthreads();
        #pragma unroll
        for (int i = 0; i < 4; i++) {
            int loff = wid * 4096 + i * 1024;          // wave-uniform LDS base
            int row = (loff >> 7) + (lane >> 3);
            int c = lane & 7;
            int gr = row0 + row; if (gr > N_NODES - 1) gr = N_NODES - 1;
            int gc = k0 + ((c ^ (row & 7)) << 3);
            gload_lds16(A + (size_t)gr * IN_FEATS + gc, As + loff + lane * 16);
        }
        #pragma unroll
        for (int i = 0; i < 2; i++) {
            int loff = wid * 2048 + i * 1024;
            int row = (loff >> 7) + (lane >> 3);
            int c = lane & 7;
            int gc = k0 + ((c ^ (row & 7)) << 3);
            gload_lds16(B + (size_t)(col0 + row) * IN_FEATS + gc, Bs + loff + lane * 16);
        }
        asm volatile("s_waitcnt vmcnt(0)" ::: "memory");
        __syncthreads();
        #pragma unroll
        for (int kk = 0; kk < 2; kk++) {
            bf16x8 af[4], bfr[2];
            const int g = kk * 4 + (lane >> 4);        // 16B k-chunk index
            #pragma unroll
            for (int fm = 0; fm < 4; fm++) {
                int row = wr * 64 + fm * 16 + (lane & 15);
                af[fm] = *(const bf16x8*)(As + row * 128 + ((g ^ (row & 7)) << 4));
            }
            #pragma unroll
            for (int fn = 0; fn < 2; fn++) {
                int row = wc * 32 + fn * 16 + (lane & 15);
                bfr[fn] = *(const bf16x8*)(Bs + row * 128 + ((g ^ (row & 7)) << 4));
            }
            #pragma unroll
            for (int fm = 0; fm < 4; fm++)
                #pragma unroll
                for (int fn = 0; fn < 2; fn++)
                    acc[fm][fn] = __builtin_amdgcn_mfma_f32_16x16x32_bf16(
                        af[fm], bfr[fn], acc[fm][fn], 0, 0, 0);
        }
    }
    // epilogue 1: C store. C/D map col=lane&15, row=(lane>>4)*4+r  [m89-verified]
    #pragma unroll
    for (int fm = 0; fm < 4; fm++) {
        #pragma unroll
        for (int r = 0; r < 4; r++) {
            int row = row0 + wr * 64 + fm * 16 + (lane >> 4) * 4 + r;
            if (row < N_NODES) {
                #pragma unroll
                for (int fn = 0; fn < 2; fn++) {
                    int col = col0 + wc * 32 + fn * 16 + (lane & 15);
                    Cb[(size_t)row * HD + col] = f2bf(acc[fm][fn][r]);
                }
            }
        }
    }
    // epilogue 2: el/er. This wave's 64 cols = head h's 32 dims (fn*16 + lane&15).
    const int h = col0 / 32 + wc;
    const int d0 = lane & 15;
    const float al0 = attn_l[h * 32 + d0],  al1 = attn_l[h * 32 + d0 + 16];
    const float ar0 = attn_r[h * 32 + d0],  ar1 = attn_r[h * 32 + d0 + 16];
    #pragma unroll
    for (int fm = 0; fm < 4; fm++) {
        #pragma unroll
        for (int r = 0; r < 4; r++) {
            float sl = acc[fm][0][r] * al0 + acc[fm][1][r] * al1;
            float sr = acc[fm][0][r] * ar0 + acc[fm][1][r] * ar1;
            #pragma unroll
            for (int m = 1; m <= 8; m <<= 1) {
                sl += __shfl_xor(sl, m);
                sr += __shfl_xor(sr, m);
            }
            int row = row0 + wr * 64 + fm * 16 + (lane >> 4) * 4 + r;
            if (d0 == 0 && row < N_NODES) {
                el[row * 8 + h] = sl;
                er[row * 8 + h] = sr;
            }
        }
    }
}

// ---------------------------------------------------------------------------
// Kernel 4: exclusive scan of counts -> offsets (+ cursor). One block.
// ---------------------------------------------------------------------------
__global__ void scan_kernel(const int* __restrict__ counts, int* __restrict__ offsets,
                            int* __restrict__ cursor) {
    __shared__ int sums[1024];
    const int T = 1024;
    const int per = (N_NODES + T - 1) / T;
    int t = threadIdx.x;
    int beg = t * per;
    int end = beg + per; if (end > N_NODES) end = N_NODES;
    int s = 0;
    for (int i = beg; i < end; i++) s += counts[i];
    sums[t] = s;
    __syncthreads();
    for (int off = 1; off < T; off <<= 1) {
        int v = (t >= off) ? sums[t - off] : 0;
        __syncthreads();
        sums[t] += v;
        __syncthreads();
    }
    int run = sums[t] - s;
    for (int i = beg; i < end; i++) {
        offsets[i] = run; cursor[i] = run;
        run += counts[i];
    }
}

// Kernel 5: scatter edge ids into CSR order
__global__ void scatter_kernel(const int* __restrict__ dst, int* __restrict__ cursor,
                               int* __restrict__ sorted_eid) {
    int e = blockIdx.x * blockDim.x + threadIdx.x;
    if (e >= N_EDGES) return;
    int pos = atomicAdd(&cursor[dst[e]], 1);
    sorted_eid[pos] = e;
}

// ---------------------------------------------------------------------------
// Kernel 6: fused per-node softmax + aggregation. One wave per dst node.
// Softmax lanes: (e_local = lane>>3, h = lane&7).
// Aggregation lanes: edge-half el2 = lane>>5, q = lane&31 -> head q>>2,
// dims (q&3)*8 .. +7 (16B ushort8 load; 32 lanes cover one 512B row).
// ---------------------------------------------------------------------------
__global__ __launch_bounds__(256) void node_fused(
    const int* __restrict__ offsets, const int* __restrict__ counts,
    const int* __restrict__ sorted, const int* __restrict__ src,
    const int* __restrict__ etype,
    const float* __restrict__ el, const float* __restrict__ er,
    const float* __restrict__ ee_tab, const float* __restrict__ w_r,
    const unsigned short* __restrict__ fsb,
    float* __restrict__ rst, float* __restrict__ aOut) {
    __shared__ float eeS[64];
    __shared__ float wrS[8];
    __shared__ float lgS[4][64][8];   // per-wave logit cache, then 'a' staging
    __shared__ int   sS[4][8];
    if (threadIdx.x < 64) eeS[threadIdx.x] = ee_tab[threadIdx.x];
    if (threadIdx.x < 8)  wrS[threadIdx.x] = w_r[threadIdx.x];
    __syncthreads();
    const int wv = threadIdx.x >> 6, lane = threadIdx.x & 63;
    const int node = blockIdx.x * 4 + wv;
    if (node >= N_NODES) return;
    const int beg = offsets[node], cnt = counts[node];
    const int e_l = lane >> 3, h = lane & 7;
    const float er_v = er[node * 8 + h];
    const int nch = (cnt + 7) >> 3;

    // pass A: logits -> LDS cache, per-lane max
    float m = -1e30f;
    for (int ch = 0; ch < nch; ch++) {
        int idx = ch * 8 + e_l;
        float lg = -1e30f;
        if (idx < cnt) {
            int eid = sorted[beg + idx];
            int s = src[eid], t = etype[eid];
            float x = el[s * 8 + h] + er_v + eeS[t * 8 + h];
            x = (x > 0.f) ? x : NEG_SLOPE * x;
            lg = x * wrS[t];
        }
        if (idx < 64) lgS[wv][idx][h] = lg;
        m = fmaxf(m, lg);
    }
    m = fmaxf(m, __shfl_xor(m, 8));
    m = fmaxf(m, __shfl_xor(m, 16));
    m = fmaxf(m, __shfl_xor(m, 32));

    // pass B: denom
    float sum = 0.f;
    for (int ch = 0; ch < nch; ch++) {
        int idx = ch * 8 + e_l;
        if (idx < cnt) {
            float lg;
            if (idx < 64) lg = lgS[wv][idx][h];
            else {
                int eid = sorted[beg + idx];
                int s = src[eid], t = etype[eid];
                float x = el[s * 8 + h] + er_v + eeS[t * 8 + h];
                x = (x > 0.f) ? x : NEG_SLOPE * x;
                lg = x * wrS[t];
            }
            sum += __expf(lg - m);
        }
    }
    sum += __shfl_xor(sum, 8);
    sum += __shfl_xor(sum, 16);
    sum += __shfl_xor(sum, 32);
    const float inv = 1.f / sum;   // cnt==0 -> unused

    // pass C: a = ex*inv -> write aOut + stage in LDS; aggregate 2 edges/iter
    float acc[8] = {};
    const int el2 = lane >> 5;          // which edge of the pair
    const int q = lane & 31;            // head = q>>2, dim octet = q&3
    const int fs_off = (q >> 2) * OUT_FEATS + (q & 3) * 8;
    const int hq = q >> 2;
    for (int ch = 0; ch < nch; ch++) {
        int idx = ch * 8 + e_l;
        float a = 0.f; int s = 0;
        if (idx < cnt) {
            int eid = sorted[beg + idx];
            s = src[eid];
            float lg;
            if (idx < 64) lg = lgS[wv][idx][h];
            else {
                int t = etype[eid];
                float x = el[s * 8 + h] + er_v + eeS[t * 8 + h];
                x = (x > 0.f) ? x : NEG_SLOPE * x;
                lg = x * wrS[t];
            }
            a = __expf(lg - m) * inv;
            aOut[(size_t)eid * 8 + h] = a;
        }
        lgS[wv][idx & 63][h] = a;           // own slot (a=0 pad for idx>=cnt)
        if (h == 0) sS[wv][e_l] = s;        // s=0 pad for idx>=cnt
        const int base = (ch * 8) & 63;
        #pragma unroll
        for (int j = 0; j < 8; j += 2) {    // fixed trip: full unroll, 4 wide loads
            int jj = j + el2;
            int sj = sS[wv][jj];
            float av = lgS[wv][base + jj][hq];
            ushort8_t u = *(const ushort8_t*)(fsb + (size_t)sj * HD + fs_off);
            #pragma unroll
            for (int d = 0; d < 8; d++)
                acc[d] = fmaf(av, bf2f(u[d]), acc[d]);
        }
    }
    #pragma unroll
    for (int d = 0; d < 8; d++) acc[d] += __shfl_xor(acc[d], 32);
    // lanes 0-31 write dims 0-3 of their octet; lanes 32-63 write dims 4-7
    *(float4*)(rst + (size_t)node * HD + q * 8 + el2 * 4) =
        make_float4(acc[el2 * 4 + 0], acc[el2 * 4 + 1], acc[el2 * 4 + 2], acc[el2 * 4 + 3]);
}

// ---------------------------------------------------------------------------
extern "C" void kernel_launch(void* const* d_in, const int* in_sizes, int n_in,
                              void* d_out, int out_size, void* d_ws, size_t ws_size,
                              hipStream_t stream) {
    const float* feat     = (const float*)d_in[0];
    const int*   e_feat   = (const int*)  d_in[1];
    const int*   src      = (const int*)  d_in[2];
    const int*   dst      = (const int*)  d_in[3];
    const float* fc_W     = (const float*)d_in[4];
    const float* edge_emb = (const float*)d_in[5];
    const float* w_r      = (const float*)d_in[6];
    const float* W1       = (const float*)d_in[7];
    const float* b1       = (const float*)d_in[8];
    const float* W2       = (const float*)d_in[9];
    const float* b2       = (const float*)d_in[10];
    const float* attn_l   = (const float*)d_in[11];
    const float* attn_r   = (const float*)d_in[12];
    const float* attn_e   = (const float*)d_in[13];

    char* ws = (char*)d_ws;
    unsigned short* featb  = (unsigned short*)(ws + 0);           // 15,360,000
    unsigned short* fsb    = (unsigned short*)(ws + 15360000);    // 15,360,000
    float*          el     = (float*)(ws + 30720000);             //    960,000
    float*          er     = (float*)(ws + 31680000);             //    960,000
    unsigned short* fcWb   = (unsigned short*)(ws + 32640000);    //    131,072
    float*          ee_tab = (float*)(ws + 32771072);             //        256
    int*            counts = (int*)(ws + 32771328);               //    120,000 (zeroed)
    int*            offs   = (int*)(ws + 32891328);               //    120,000
    int*            cursor = (int*)(ws + 33011328);               //    120,000
    int*            sorted = (int*)(ws + 33131328);               //  1,920,000
    float*          h1_ws  = (float*)(ws + 35051328);             //      4,096
    float*          M_ws   = (float*)(ws + 35055424);             //      4,096

    float* rst  = (float*)d_out;                     // [30000,8,32]
    float* aOut = rst + (size_t)N_NODES * HD;        // [480000,8]

    hipMemsetAsync(counts, 0, 120000, stream);
    ee_mid<<<8, 256, 0, stream>>>(edge_emb, W1, b1, W2, attn_e, h1_ws, M_ws);
    ee_fin<<<1, 64, 0, stream>>>(h1_ws, M_ws, attn_e, b2, ee_tab);
    cvt_hist<<<2048, 256, 0, stream>>>(feat, fc_W, dst, featb, fcWb, counts);
    scan_kernel<<<1, 1024, 0, stream>>>(counts, offs, cursor);
    scatter_kernel<<<(N_EDGES + 255) / 256, 256, 0, stream>>>(dst, cursor, sorted);
    gemm_bf16<<<dim3((N_NODES + GBM - 1) / GBM, HD / GBN), 256, 0, stream>>>(
        featb, fcWb, attn_l, attn_r, fsb, el, er);
    node_fused<<<(N_NODES + 3) / 4, 256, 0, stream>>>(
        offs, counts, sorted, src, e_feat, el, er, ee_tab, w_r, fsb, rst, aOut);
}

// Round 6
// 276.062 us; speedup vs baseline: 1.9104x; 1.0945x over previous
//
#include <hip/hip_runtime.h>
#include <math.h>

#define N_NODES 30000
#define N_EDGES 480000
#define IN_FEATS 256
#define N_HEADS 8
#define OUT_FEATS 32
#define EDGE_FEATS 64
#define NUM_ETYPES 8
#define NEG_SLOPE 0.2f
#define HD 256  // N_HEADS*OUT_FEATS

typedef __bf16 bf16_t;
typedef bf16_t bf16x8 __attribute__((ext_vector_type(8)));
typedef float f32x4 __attribute__((ext_vector_type(4)));
typedef unsigned short ushort8_t __attribute__((ext_vector_type(8)));

__device__ __forceinline__ unsigned short f2bf(float f) {
    unsigned u = __float_as_uint(f);
    u += 0x7fffu + ((u >> 16) & 1u);   // round-to-nearest-even
    return (unsigned short)(u >> 16);
}
__device__ __forceinline__ float bf2f(unsigned short s) {
    return __uint_as_float(((unsigned)s) << 16);
}

__device__ __forceinline__ void gload_lds16(const void* g, void* l) {
    __builtin_amdgcn_global_load_lds(
        (const __attribute__((address_space(1))) unsigned int*)g,
        (__attribute__((address_space(3))) unsigned int*)l, 16, 0, 0);
}

// ---------------------------------------------------------------------------
// Kernel 1: full ee-table precompute in ONE block (1024 threads).
//   phase 1: h1[t][r] (1024 items) and M[h][k] (1024 items) -> LDS
//   phase 2: ee[t][h] = c[h] + dot(M[h,:], h1[t,:])  (64 threads)
// ---------------------------------------------------------------------------
__global__ __launch_bounds__(1024) void ee_all(
    const float* __restrict__ edge_emb,
    const float* __restrict__ W1, const float* __restrict__ b1,
    const float* __restrict__ W2, const float* __restrict__ b2,
    const float* __restrict__ attn_e, float* __restrict__ ee_tab) {
    __shared__ float h1S[1024];   // [t][r] t=etype, r=0..127
    __shared__ float MS[1024];    // [h][k] h=head,  k=0..127
    const int t0 = threadIdx.x;
    {   // i = t0 -> h1 path
        int t = t0 >> 7, r = t0 & 127;
        const float4* Wv = (const float4*)(W1 + (size_t)r * EDGE_FEATS);
        const float4* Ev = (const float4*)(edge_emb + (size_t)t * EDGE_FEATS);
        float s = b1[r];
        #pragma unroll
        for (int q = 0; q < 16; q++) {
            float4 w = Wv[q], e = Ev[q];
            s += w.x * e.x + w.y * e.y + w.z * e.z + w.w * e.w;
        }
        h1S[t0] = fmaxf(s, 0.f);
    }
    {   // i = t0+1024 -> M path (coalesced W2 reads: lanes consecutive in k)
        int h = t0 >> 7, k = t0 & 127;
        float s = 0.f;
        #pragma unroll 8
        for (int f = 0; f < EDGE_FEATS; f++)
            s = fmaf(attn_e[h * EDGE_FEATS + f],
                     W2[(size_t)(h * EDGE_FEATS + f) * (2 * EDGE_FEATS) + k], s);
        MS[t0] = s;
    }
    __syncthreads();
    if (t0 < 64) {
        int t = t0 >> 3, h = t0 & 7;
        float s = 0.f;
        for (int f = 0; f < EDGE_FEATS; f++)
            s = fmaf(attn_e[h * EDGE_FEATS + f], b2[h * EDGE_FEATS + f], s);
        for (int k = 0; k < 2 * EDGE_FEATS; k++)
            s = fmaf(MS[h * 128 + k], h1S[t * 128 + k], s);
        ee_tab[t0] = s;
    }
}

// ---------------------------------------------------------------------------
// Kernel 2: fp32->bf16 conversion (feat, fc_W) + dst histogram, fused.
// ---------------------------------------------------------------------------
__global__ void cvt_hist(const float* __restrict__ feat, const float* __restrict__ fcW,
                         const int* __restrict__ dst,
                         unsigned short* __restrict__ featb, unsigned short* __restrict__ fcWb,
                         int* __restrict__ counts) {
    const int n1 = N_NODES * IN_FEATS / 4;      // 1,920,000 float4 groups
    const int n2 = IN_FEATS * HD / 4;           // 16,384
    const int tid0 = blockIdx.x * blockDim.x + threadIdx.x;
    const int stride = gridDim.x * blockDim.x;
    for (int i = tid0; i < n1 + n2; i += stride) {
        float4 v = (i < n1) ? ((const float4*)feat)[i] : ((const float4*)fcW)[i - n1];
        ushort4 o;
        o.x = f2bf(v.x); o.y = f2bf(v.y); o.z = f2bf(v.z); o.w = f2bf(v.w);
        if (i < n1) ((ushort4*)featb)[i] = o;
        else        ((ushort4*)fcWb)[i - n1] = o;
    }
    for (int e = tid0; e < N_EDGES; e += stride)
        atomicAdd(&counts[dst[e]], 1);
}

// ---------------------------------------------------------------------------
// Kernel 3: bf16 MFMA GEMM  C = feat @ fc_W^T  -> bf16 feat_src [30000][256]
// + fused el/er epilogue (each wave owns exactly one head's 32 cols).
// ---------------------------------------------------------------------------
#define GBM 128
#define GBN 64
#define GBK 64
__global__ __launch_bounds__(256) void gemm_bf16(const unsigned short* __restrict__ A,
                                                 const unsigned short* __restrict__ B,
                                                 const float* __restrict__ attn_l,
                                                 const float* __restrict__ attn_r,
                                                 unsigned short* __restrict__ Cb,
                                                 float* __restrict__ el,
                                                 float* __restrict__ er) {
    __shared__ __align__(16) unsigned char As[GBM * GBK * 2];  // 16 KiB, XOR-swizzled rows
    __shared__ __align__(16) unsigned char Bs[GBN * GBK * 2];  //  8 KiB
    const int tid = threadIdx.x;
    const int lane = tid & 63;
    const int wid = tid >> 6;
    const int wr = wid >> 1, wc = wid & 1;
    const int row0 = blockIdx.x * GBM;
    const int col0 = blockIdx.y * GBN;

    f32x4 acc[4][2] = {};

    for (int k0 = 0; k0 < IN_FEATS; k0 += GBK) {
        __syncthreads();
        #pragma unroll
        for (int i = 0; i < 4; i++) {
            int loff = wid * 4096 + i * 1024;          // wave-uniform LDS base
            int row = (loff >> 7) + (lane >> 3);
            int c = lane & 7;
            int gr = row0 + row; if (gr > N_NODES - 1) gr = N_NODES - 1;
            int gc = k0 + ((c ^ (row & 7)) << 3);
            gload_lds16(A + (size_t)gr * IN_FEATS + gc, As + loff + lane * 16);
        }
        #pragma unroll
        for (int i = 0; i < 2; i++) {
            int loff = wid * 2048 + i * 1024;
            int row = (loff >> 7) + (lane >> 3);
            int c = lane & 7;
            int gc = k0 + ((c ^ (row & 7)) << 3);
            gload_lds16(B + (size_t)(col0 + row) * IN_FEATS + gc, Bs + loff + lane * 16);
        }
        asm volatile("s_waitcnt vmcnt(0)" ::: "memory");
        __syncthreads();
        #pragma unroll
        for (int kk = 0; kk < 2; kk++) {
            bf16x8 af[4], bfr[2];
            const int g = kk * 4 + (lane >> 4);        // 16B k-chunk index
            #pragma unroll
            for (int fm = 0; fm < 4; fm++) {
                int row = wr * 64 + fm * 16 + (lane & 15);
                af[fm] = *(const bf16x8*)(As + row * 128 + ((g ^ (row & 7)) << 4));
            }
            #pragma unroll
            for (int fn = 0; fn < 2; fn++) {
                int row = wc * 32 + fn * 16 + (lane & 15);
                bfr[fn] = *(const bf16x8*)(Bs + row * 128 + ((g ^ (row & 7)) << 4));
            }
            #pragma unroll
            for (int fm = 0; fm < 4; fm++)
                #pragma unroll
                for (int fn = 0; fn < 2; fn++)
                    acc[fm][fn] = __builtin_amdgcn_mfma_f32_16x16x32_bf16(
                        af[fm], bfr[fn], acc[fm][fn], 0, 0, 0);
        }
    }
    // epilogue 1: C store. C/D map col=lane&15, row=(lane>>4)*4+r  [m89-verified]
    #pragma unroll
    for (int fm = 0; fm < 4; fm++) {
        #pragma unroll
        for (int r = 0; r < 4; r++) {
            int row = row0 + wr * 64 + fm * 16 + (lane >> 4) * 4 + r;
            if (row < N_NODES) {
                #pragma unroll
                for (int fn = 0; fn < 2; fn++) {
                    int col = col0 + wc * 32 + fn * 16 + (lane & 15);
                    Cb[(size_t)row * HD + col] = f2bf(acc[fm][fn][r]);
                }
            }
        }
    }
    // epilogue 2: el/er. This wave's 64 cols = head h's 32 dims (fn*16 + lane&15).
    const int h = col0 / 32 + wc;
    const int d0 = lane & 15;
    const float al0 = attn_l[h * 32 + d0],  al1 = attn_l[h * 32 + d0 + 16];
    const float ar0 = attn_r[h * 32 + d0],  ar1 = attn_r[h * 32 + d0 + 16];
    #pragma unroll
    for (int fm = 0; fm < 4; fm++) {
        #pragma unroll
        for (int r = 0; r < 4; r++) {
            float sl = acc[fm][0][r] * al0 + acc[fm][1][r] * al1;
            float sr = acc[fm][0][r] * ar0 + acc[fm][1][r] * ar1;
            #pragma unroll
            for (int m = 1; m <= 8; m <<= 1) {
                sl += __shfl_xor(sl, m);
                sr += __shfl_xor(sr, m);
            }
            int row = row0 + wr * 64 + fm * 16 + (lane >> 4) * 4 + r;
            if (d0 == 0 && row < N_NODES) {
                el[row * 8 + h] = sl;
                er[row * 8 + h] = sr;
            }
        }
    }
}

// ---------------------------------------------------------------------------
// Kernel 4: exclusive scan via full LDS staging (coalesced global traffic).
// 30720 ints staged (124 KiB static LDS, 1 block/CU — fine, single block).
// ---------------------------------------------------------------------------
__global__ __launch_bounds__(1024) void scan_kernel(const int* __restrict__ counts,
                                                    int* __restrict__ offsets,
                                                    int* __restrict__ cursor) {
    __shared__ int buf[30720];
    __shared__ int sums[1024];
    const int t = threadIdx.x;
    const int per = 30;
    for (int i = t; i < 30720; i += 1024)
        buf[i] = (i < N_NODES) ? counts[i] : 0;
    __syncthreads();
    int s = 0;
    #pragma unroll
    for (int i = 0; i < per; i++) s += buf[t * per + i];
    sums[t] = s;
    __syncthreads();
    for (int off = 1; off < 1024; off <<= 1) {
        int v = (t >= off) ? sums[t - off] : 0;
        __syncthreads();
        sums[t] += v;
        __syncthreads();
    }
    int run = sums[t] - s;   // exclusive prefix of this chunk
    #pragma unroll
    for (int i = 0; i < per; i++) {
        int c = buf[t * per + i];
        buf[t * per + i] = run;
        run += c;
    }
    __syncthreads();
    for (int i = t; i < N_NODES; i += 1024) {
        int v = buf[i];
        offsets[i] = v; cursor[i] = v;
    }
}

// Kernel 5: scatter edge ids into CSR order
__global__ void scatter_kernel(const int* __restrict__ dst, int* __restrict__ cursor,
                               int* __restrict__ sorted_eid) {
    int e = blockIdx.x * blockDim.x + threadIdx.x;
    if (e >= N_EDGES) return;
    int pos = atomicAdd(&cursor[dst[e]], 1);
    sorted_eid[pos] = e;
}

// ---------------------------------------------------------------------------
// Kernel 6: fused per-node softmax + aggregation. One wave per node,
// persistent grid-stride over nodes. Softmax lanes (e_l=lane>>3, h=lane&7);
// aggregation: pair-half el2=lane>>5, q=lane&31 -> head q>>2, dim octet q&3.
// Pass C uses __shfl (not LDS) to move (s, a) softmax->agg layout.
// ---------------------------------------------------------------------------
__global__ __launch_bounds__(256) void node_fused(
    const int* __restrict__ offsets, const int* __restrict__ counts,
    const int* __restrict__ sorted, const int* __restrict__ src,
    const int* __restrict__ etype,
    const float* __restrict__ el, const float* __restrict__ er,
    const float* __restrict__ ee_tab, const float* __restrict__ w_r,
    const unsigned short* __restrict__ fsb,
    float* __restrict__ rst, float* __restrict__ aOut) {
    __shared__ float eeS[64];
    __shared__ float wrS[8];
    __shared__ float lgS[4][64][8];   // per-wave logit cache
    if (threadIdx.x < 64) eeS[threadIdx.x] = ee_tab[threadIdx.x];
    if (threadIdx.x < 8)  wrS[threadIdx.x] = w_r[threadIdx.x];
    __syncthreads();
    const int wv = threadIdx.x >> 6, lane = threadIdx.x & 63;
    const int e_l = lane >> 3, h = lane & 7;
    const int el2 = lane >> 5;
    const int q = lane & 31;
    const int hq = q >> 2;
    const int fs_off = hq * OUT_FEATS + (q & 3) * 8;
    const int nstride = (int)gridDim.x * 4;

    for (int node = blockIdx.x * 4 + wv; node < N_NODES; node += nstride) {
        const int beg = offsets[node], cnt = counts[node];
        const float er_v = er[node * 8 + h];
        const int nch = (cnt + 7) >> 3;

        // pass A: logits -> LDS cache, per-lane max
        float m = -1e30f;
        for (int ch = 0; ch < nch; ch++) {
            int idx = ch * 8 + e_l;
            float lg = -1e30f;
            if (idx < cnt) {
                int eid = sorted[beg + idx];
                int s = src[eid], t = etype[eid];
                float x = el[s * 8 + h] + er_v + eeS[t * 8 + h];
                x = (x > 0.f) ? x : NEG_SLOPE * x;
                lg = x * wrS[t];
            }
            if (idx < 64) lgS[wv][idx][h] = lg;
            m = fmaxf(m, lg);
        }
        m = fmaxf(m, __shfl_xor(m, 8));
        m = fmaxf(m, __shfl_xor(m, 16));
        m = fmaxf(m, __shfl_xor(m, 32));

        // pass B: denom
        float sum = 0.f;
        for (int ch = 0; ch < nch; ch++) {
            int idx = ch * 8 + e_l;
            if (idx < cnt) {
                float lg;
                if (idx < 64) lg = lgS[wv][idx][h];
                else {
                    int eid = sorted[beg + idx];
                    int s = src[eid], t = etype[eid];
                    float x = el[s * 8 + h] + er_v + eeS[t * 8 + h];
                    x = (x > 0.f) ? x : NEG_SLOPE * x;
                    lg = x * wrS[t];
                }
                sum += __expf(lg - m);
            }
        }
        sum += __shfl_xor(sum, 8);
        sum += __shfl_xor(sum, 16);
        sum += __shfl_xor(sum, 32);
        const float inv = 1.f / sum;   // cnt==0 -> unused

        // pass C: a = ex*inv -> aOut; shuffle (s,a) to agg layout; gather rows
        float acc[8] = {};
        for (int ch = 0; ch < nch; ch++) {
            int idx = ch * 8 + e_l;
            float a = 0.f; int s = 0;
            if (idx < cnt) {
                int eid = sorted[beg + idx];
                s = src[eid];
                float lg;
                if (idx < 64) lg = lgS[wv][idx][h];
                else {
                    int t = etype[eid];
                    float x = el[s * 8 + h] + er_v + eeS[t * 8 + h];
                    x = (x > 0.f) ? x : NEG_SLOPE * x;
                    lg = x * wrS[t];
                }
                a = __expf(lg - m) * inv;
                aOut[(size_t)eid * 8 + h] = a;
            }
            #pragma unroll
            for (int j = 0; j < 8; j += 2) {   // 4 iters x 2 edges (wave halves)
                int jj = j + el2;
                int sj = __shfl(s, jj * 8);           // s from (idx=jj, h=0) lane
                float av = __shfl(a, jj * 8 + hq);    // a from (idx=jj, h=hq) lane
                ushort8_t u = *(const ushort8_t*)(fsb + (size_t)sj * HD + fs_off);
                #pragma unroll
                for (int d = 0; d < 8; d++)
                    acc[d] = fmaf(av, bf2f(u[d]), acc[d]);
            }
        }
        #pragma unroll
        for (int d = 0; d < 8; d++) acc[d] += __shfl_xor(acc[d], 32);
        *(float4*)(rst + (size_t)node * HD + q * 8 + el2 * 4) =
            make_float4(acc[el2 * 4 + 0], acc[el2 * 4 + 1],
                        acc[el2 * 4 + 2], acc[el2 * 4 + 3]);
    }
}

// ---------------------------------------------------------------------------
extern "C" void kernel_launch(void* const* d_in, const int* in_sizes, int n_in,
                              void* d_out, int out_size, void* d_ws, size_t ws_size,
                              hipStream_t stream) {
    const float* feat     = (const float*)d_in[0];
    const int*   e_feat   = (const int*)  d_in[1];
    const int*   src      = (const int*)  d_in[2];
    const int*   dst      = (const int*)  d_in[3];
    const float* fc_W     = (const float*)d_in[4];
    const float* edge_emb = (const float*)d_in[5];
    const float* w_r      = (const float*)d_in[6];
    const float* W1       = (const float*)d_in[7];
    const float* b1       = (const float*)d_in[8];
    const float* W2       = (const float*)d_in[9];
    const float* b2       = (const float*)d_in[10];
    const float* attn_l   = (const float*)d_in[11];
    const float* attn_r   = (const float*)d_in[12];
    const float* attn_e   = (const float*)d_in[13];

    char* ws = (char*)d_ws;
    unsigned short* featb  = (unsigned short*)(ws + 0);           // 15,360,000
    unsigned short* fsb    = (unsigned short*)(ws + 15360000);    // 15,360,000
    float*          el     = (float*)(ws + 30720000);             //    960,000
    float*          er     = (float*)(ws + 31680000);             //    960,000
    unsigned short* fcWb   = (unsigned short*)(ws + 32640000);    //    131,072
    float*          ee_tab = (float*)(ws + 32771072);             //        256
    int*            counts = (int*)(ws + 32771328);               //    120,000 (zeroed)
    int*            offs   = (int*)(ws + 32891328);               //    120,000
    int*            cursor = (int*)(ws + 33011328);               //    120,000
    int*            sorted = (int*)(ws + 33131328);               //  1,920,000

    float* rst  = (float*)d_out;                     // [30000,8,32]
    float* aOut = rst + (size_t)N_NODES * HD;        // [480000,8]

    hipMemsetAsync(counts, 0, 120000, stream);
    ee_all<<<1, 1024, 0, stream>>>(edge_emb, W1, b1, W2, b2, attn_e, ee_tab);
    cvt_hist<<<2048, 256, 0, stream>>>(feat, fc_W, dst, featb, fcWb, counts);
    scan_kernel<<<1, 1024, 0, stream>>>(counts, offs, cursor);
    scatter_kernel<<<(N_EDGES + 255) / 256, 256, 0, stream>>>(dst, cursor, sorted);
    gemm_bf16<<<dim3((N_NODES + GBM - 1) / GBM, HD / GBN), 256, 0, stream>>>(
        featb, fcWb, attn_l, attn_r, fsb, el, er);
    node_fused<<<2048, 256, 0, stream>>>(
        offs, counts, sorted, src, e_feat, el, er, ee_tab, w_r, fsb, rst, aOut);
}

// Round 7
// 256.816 us; speedup vs baseline: 2.0535x; 1.0749x over previous
//
#include <hip/hip_runtime.h>
#include <math.h>

#define N_NODES 30000
#define N_EDGES 480000
#define IN_FEATS 256
#define N_HEADS 8
#define OUT_FEATS 32
#define EDGE_FEATS 64
#define NUM_ETYPES 8
#define NEG_SLOPE 0.2f
#define HD 256  // N_HEADS*OUT_FEATS

typedef __bf16 bf16_t;
typedef bf16_t bf16x8 __attribute__((ext_vector_type(8)));
typedef float f32x4 __attribute__((ext_vector_type(4)));

__device__ __forceinline__ unsigned short f2bf(float f) {
    unsigned u = __float_as_uint(f);
    u += 0x7fffu + ((u >> 16) & 1u);   // round-to-nearest-even
    return (unsigned short)(u >> 16);
}
__device__ __forceinline__ float bf2f(unsigned short s) {
    return __uint_as_float(((unsigned)s) << 16);
}

__device__ __forceinline__ void gload_lds16(const void* g, void* l) {
    __builtin_amdgcn_global_load_lds(
        (const __attribute__((address_space(1))) unsigned int*)g,
        (__attribute__((address_space(3))) unsigned int*)l, 16, 0, 0);
}

// ---------------------------------------------------------------------------
// Kernel 1: full ee-table precompute in ONE block (1024 threads).
// ---------------------------------------------------------------------------
__global__ __launch_bounds__(1024) void ee_all(
    const float* __restrict__ edge_emb,
    const float* __restrict__ W1, const float* __restrict__ b1,
    const float* __restrict__ W2, const float* __restrict__ b2,
    const float* __restrict__ attn_e, float* __restrict__ ee_tab) {
    __shared__ float h1S[1024];   // [t][r] t=etype, r=0..127
    __shared__ float MS[1024];    // [h][k] h=head,  k=0..127
    const int t0 = threadIdx.x;
    {   // h1 path
        int t = t0 >> 7, r = t0 & 127;
        const float4* Wv = (const float4*)(W1 + (size_t)r * EDGE_FEATS);
        const float4* Ev = (const float4*)(edge_emb + (size_t)t * EDGE_FEATS);
        float s = b1[r];
        #pragma unroll
        for (int q = 0; q < 16; q++) {
            float4 w = Wv[q], e = Ev[q];
            s += w.x * e.x + w.y * e.y + w.z * e.z + w.w * e.w;
        }
        h1S[t0] = fmaxf(s, 0.f);
    }
    {   // M path (coalesced W2 reads: lanes consecutive in k)
        int h = t0 >> 7, k = t0 & 127;
        float s = 0.f;
        #pragma unroll 8
        for (int f = 0; f < EDGE_FEATS; f++)
            s = fmaf(attn_e[h * EDGE_FEATS + f],
                     W2[(size_t)(h * EDGE_FEATS + f) * (2 * EDGE_FEATS) + k], s);
        MS[t0] = s;
    }
    __syncthreads();
    if (t0 < 64) {
        int t = t0 >> 3, h = t0 & 7;
        float s = 0.f;
        for (int f = 0; f < EDGE_FEATS; f++)
            s = fmaf(attn_e[h * EDGE_FEATS + f], b2[h * EDGE_FEATS + f], s);
        for (int k = 0; k < 2 * EDGE_FEATS; k++)
            s = fmaf(MS[h * 128 + k], h1S[t * 128 + k], s);
        ee_tab[t0] = s;
    }
}

// ---------------------------------------------------------------------------
// Kernel 2: fp32->bf16 conversion (feat, fc_W) + dst histogram, fused.
// ---------------------------------------------------------------------------
__global__ void cvt_hist(const float* __restrict__ feat, const float* __restrict__ fcW,
                         const int* __restrict__ dst,
                         unsigned short* __restrict__ featb, unsigned short* __restrict__ fcWb,
                         int* __restrict__ counts) {
    const int n1 = N_NODES * IN_FEATS / 4;      // 1,920,000 float4 groups
    const int n2 = IN_FEATS * HD / 4;           // 16,384
    const int tid0 = blockIdx.x * blockDim.x + threadIdx.x;
    const int stride = gridDim.x * blockDim.x;
    for (int i = tid0; i < n1 + n2; i += stride) {
        float4 v = (i < n1) ? ((const float4*)feat)[i] : ((const float4*)fcW)[i - n1];
        ushort4 o;
        o.x = f2bf(v.x); o.y = f2bf(v.y); o.z = f2bf(v.z); o.w = f2bf(v.w);
        if (i < n1) ((ushort4*)featb)[i] = o;
        else        ((ushort4*)fcWb)[i - n1] = o;
    }
    for (int e = tid0; e < N_EDGES; e += stride)
        atomicAdd(&counts[dst[e]], 1);
}

// ---------------------------------------------------------------------------
// Kernel 3: bf16 MFMA GEMM  C = feat @ fc_W^T  -> bf16 feat_src [30000][256]
// + fused el/er epilogue (each wave owns exactly one head's 32 cols).
// ---------------------------------------------------------------------------
#define GBM 128
#define GBN 64
#define GBK 64
__global__ __launch_bounds__(256) void gemm_bf16(const unsigned short* __restrict__ A,
                                                 const unsigned short* __restrict__ B,
                                                 const float* __restrict__ attn_l,
                                                 const float* __restrict__ attn_r,
                                                 unsigned short* __restrict__ Cb,
                                                 float* __restrict__ el,
                                                 float* __restrict__ er) {
    __shared__ __align__(16) unsigned char As[GBM * GBK * 2];  // 16 KiB, XOR-swizzled rows
    __shared__ __align__(16) unsigned char Bs[GBN * GBK * 2];  //  8 KiB
    const int tid = threadIdx.x;
    const int lane = tid & 63;
    const int wid = tid >> 6;
    const int wr = wid >> 1, wc = wid & 1;
    const int row0 = blockIdx.x * GBM;
    const int col0 = blockIdx.y * GBN;

    f32x4 acc[4][2] = {};

    for (int k0 = 0; k0 < IN_FEATS; k0 += GBK) {
        __syncthreads();
        #pragma unroll
        for (int i = 0; i < 4; i++) {
            int loff = wid * 4096 + i * 1024;          // wave-uniform LDS base
            int row = (loff >> 7) + (lane >> 3);
            int c = lane & 7;
            int gr = row0 + row; if (gr > N_NODES - 1) gr = N_NODES - 1;
            int gc = k0 + ((c ^ (row & 7)) << 3);
            gload_lds16(A + (size_t)gr * IN_FEATS + gc, As + loff + lane * 16);
        }
        #pragma unroll
        for (int i = 0; i < 2; i++) {
            int loff = wid * 2048 + i * 1024;
            int row = (loff >> 7) + (lane >> 3);
            int c = lane & 7;
            int gc = k0 + ((c ^ (row & 7)) << 3);
            gload_lds16(B + (size_t)(col0 + row) * IN_FEATS + gc, Bs + loff + lane * 16);
        }
        asm volatile("s_waitcnt vmcnt(0)" ::: "memory");
        __syncthreads();
        #pragma unroll
        for (int kk = 0; kk < 2; kk++) {
            bf16x8 af[4], bfr[2];
            const int g = kk * 4 + (lane >> 4);        // 16B k-chunk index
            #pragma unroll
            for (int fm = 0; fm < 4; fm++) {
                int row = wr * 64 + fm * 16 + (lane & 15);
                af[fm] = *(const bf16x8*)(As + row * 128 + ((g ^ (row & 7)) << 4));
            }
            #pragma unroll
            for (int fn = 0; fn < 2; fn++) {
                int row = wc * 32 + fn * 16 + (lane & 15);
                bfr[fn] = *(const bf16x8*)(Bs + row * 128 + ((g ^ (row & 7)) << 4));
            }
            #pragma unroll
            for (int fm = 0; fm < 4; fm++)
                #pragma unroll
                for (int fn = 0; fn < 2; fn++)
                    acc[fm][fn] = __builtin_amdgcn_mfma_f32_16x16x32_bf16(
                        af[fm], bfr[fn], acc[fm][fn], 0, 0, 0);
        }
    }
    // epilogue 1: C store. C/D map col=lane&15, row=(lane>>4)*4+r  [m89-verified]
    #pragma unroll
    for (int fm = 0; fm < 4; fm++) {
        #pragma unroll
        for (int r = 0; r < 4; r++) {
            int row = row0 + wr * 64 + fm * 16 + (lane >> 4) * 4 + r;
            if (row < N_NODES) {
                #pragma unroll
                for (int fn = 0; fn < 2; fn++) {
                    int col = col0 + wc * 32 + fn * 16 + (lane & 15);
                    Cb[(size_t)row * HD + col] = f2bf(acc[fm][fn][r]);
                }
            }
        }
    }
    // epilogue 2: el/er. This wave's 64 cols = head h's 32 dims.
    const int h = col0 / 32 + wc;
    const int d0 = lane & 15;
    const float al0 = attn_l[h * 32 + d0],  al1 = attn_l[h * 32 + d0 + 16];
    const float ar0 = attn_r[h * 32 + d0],  ar1 = attn_r[h * 32 + d0 + 16];
    #pragma unroll
    for (int fm = 0; fm < 4; fm++) {
        #pragma unroll
        for (int r = 0; r < 4; r++) {
            float sl = acc[fm][0][r] * al0 + acc[fm][1][r] * al1;
            float sr = acc[fm][0][r] * ar0 + acc[fm][1][r] * ar1;
            #pragma unroll
            for (int m = 1; m <= 8; m <<= 1) {
                sl += __shfl_xor(sl, m);
                sr += __shfl_xor(sr, m);
            }
            int row = row0 + wr * 64 + fm * 16 + (lane >> 4) * 4 + r;
            if (d0 == 0 && row < N_NODES) {
                el[row * 8 + h] = sl;
                er[row * 8 + h] = sr;
            }
        }
    }
}

// ---------------------------------------------------------------------------
// Kernel 4: exclusive scan via full LDS staging (coalesced global traffic).
// ---------------------------------------------------------------------------
__global__ __launch_bounds__(1024) void scan_kernel(const int* __restrict__ counts,
                                                    int* __restrict__ offsets,
                                                    int* __restrict__ cursor) {
    __shared__ int buf[30720];
    __shared__ int sums[1024];
    const int t = threadIdx.x;
    const int per = 30;
    for (int i = t; i < 30720; i += 1024)
        buf[i] = (i < N_NODES) ? counts[i] : 0;
    __syncthreads();
    int s = 0;
    #pragma unroll
    for (int i = 0; i < per; i++) s += buf[t * per + i];
    sums[t] = s;
    __syncthreads();
    for (int off = 1; off < 1024; off <<= 1) {
        int v = (t >= off) ? sums[t - off] : 0;
        __syncthreads();
        sums[t] += v;
        __syncthreads();
    }
    int run = sums[t] - s;   // exclusive prefix of this chunk
    #pragma unroll
    for (int i = 0; i < per; i++) {
        int c = buf[t * per + i];
        buf[t * per + i] = run;
        run += c;
    }
    __syncthreads();
    for (int i = t; i < N_NODES; i += 1024) {
        int v = buf[i];
        offsets[i] = v; cursor[i] = v;
    }
}

// ---------------------------------------------------------------------------
// Kernel 5: scatter packed CSR records {src*8+etype, eid} (one 8B store).
// ---------------------------------------------------------------------------
__global__ void scatter_kernel(const int* __restrict__ dst, const int* __restrict__ src,
                               const int* __restrict__ etype, int* __restrict__ cursor,
                               int2* __restrict__ sorted2) {
    int e = blockIdx.x * blockDim.x + threadIdx.x;
    if (e >= N_EDGES) return;
    int pos = atomicAdd(&cursor[dst[e]], 1);
    sorted2[pos] = make_int2(src[e] * 8 + etype[e], e);
}

// ---------------------------------------------------------------------------
// Kernel 6: fused per-node softmax + aggregation. One wave per dst node.
// Softmax lanes: (e_l = lane>>3, h = lane&7); aggregation: lane owns dims
// lane*4..lane*4+3 (head hq = lane>>3). r4-proven LDS-staged pass C.
// CSR record is pre-packed: one coalesced 8B load gives (src, etype, eid).
// ---------------------------------------------------------------------------
__global__ __launch_bounds__(256) void node_fused(
    const int* __restrict__ offsets, const int* __restrict__ counts,
    const int2* __restrict__ sorted2,
    const float* __restrict__ el, const float* __restrict__ er,
    const float* __restrict__ ee_tab, const float* __restrict__ w_r,
    const unsigned short* __restrict__ fsb,
    float* __restrict__ rst, float* __restrict__ aOut) {
    __shared__ float eeS[64];
    __shared__ float wrS[8];
    __shared__ float lgS[4][64][8];   // per-wave logit cache, then 'a' staging
    __shared__ int   sS[4][8];
    if (threadIdx.x < 64) eeS[threadIdx.x] = ee_tab[threadIdx.x];
    if (threadIdx.x < 8)  wrS[threadIdx.x] = w_r[threadIdx.x];
    __syncthreads();
    const int wv = threadIdx.x >> 6, lane = threadIdx.x & 63;
    const int node = blockIdx.x * 4 + wv;
    if (node >= N_NODES) return;
    const int beg = offsets[node], cnt = counts[node];
    const int e_l = lane >> 3, h = lane & 7;
    const float er_v = er[node * 8 + h];
    const int nch = (cnt + 7) >> 3;

    // pass A: logits -> LDS cache, per-lane max
    float m = -1e30f;
    for (int ch = 0; ch < nch; ch++) {
        int idx = ch * 8 + e_l;
        float lg = -1e30f;
        if (idx < cnt) {
            int2 p = sorted2[beg + idx];
            int s = p.x >> 3, t = p.x & 7;
            float x = el[s * 8 + h] + er_v + eeS[t * 8 + h];
            x = (x > 0.f) ? x : NEG_SLOPE * x;
            lg = x * wrS[t];
        }
        if (idx < 64) lgS[wv][idx][h] = lg;
        m = fmaxf(m, lg);
    }
    m = fmaxf(m, __shfl_xor(m, 8));
    m = fmaxf(m, __shfl_xor(m, 16));
    m = fmaxf(m, __shfl_xor(m, 32));

    // pass B: denom
    float sum = 0.f;
    for (int ch = 0; ch < nch; ch++) {
        int idx = ch * 8 + e_l;
        if (idx < cnt) {
            float lg;
            if (idx < 64) lg = lgS[wv][idx][h];
            else {
                int2 p = sorted2[beg + idx];
                int s = p.x >> 3, t = p.x & 7;
                float x = el[s * 8 + h] + er_v + eeS[t * 8 + h];
                x = (x > 0.f) ? x : NEG_SLOPE * x;
                lg = x * wrS[t];
            }
            sum += __expf(lg - m);
        }
    }
    sum += __shfl_xor(sum, 8);
    sum += __shfl_xor(sum, 16);
    sum += __shfl_xor(sum, 32);
    const float inv = 1.f / sum;   // cnt==0 -> unused

    // pass C: a = ex*inv -> aOut + LDS stage; aggregate 8-edge chunk
    float acc0 = 0.f, acc1 = 0.f, acc2 = 0.f, acc3 = 0.f;
    const int hq = lane >> 3;       // aggregation head for dims lane*4..+3
    for (int ch = 0; ch < nch; ch++) {
        int idx = ch * 8 + e_l;
        float a = 0.f; int s = 0;
        if (idx < cnt) {
            int2 p = sorted2[beg + idx];
            s = p.x >> 3;
            float lg;
            if (idx < 64) lg = lgS[wv][idx][h];
            else {
                int t = p.x & 7;
                float x = el[s * 8 + h] + er_v + eeS[t * 8 + h];
                x = (x > 0.f) ? x : NEG_SLOPE * x;
                lg = x * wrS[t];
            }
            a = __expf(lg - m) * inv;
            aOut[(size_t)p.y * 8 + h] = a;
        }
        lgS[wv][idx & 63][h] = a;           // own slot (a=0 pad for idx>=cnt)
        if (h == 0) sS[wv][e_l] = s;        // s=0 pad for idx>=cnt
        int lim = cnt - ch * 8; if (lim > 8) lim = 8;
        for (int j = 0; j < lim; j++) {
            int sj = sS[wv][j];
            float av = lgS[wv][(ch * 8 + j) & 63][hq];
            ushort4 u = *(const ushort4*)(fsb + (size_t)sj * HD + lane * 4);
            acc0 = fmaf(av, bf2f(u.x), acc0);
            acc1 = fmaf(av, bf2f(u.y), acc1);
            acc2 = fmaf(av, bf2f(u.z), acc2);
            acc3 = fmaf(av, bf2f(u.w), acc3);
        }
    }
    *(float4*)(rst + (size_t)node * HD + lane * 4) = make_float4(acc0, acc1, acc2, acc3);
}

// ---------------------------------------------------------------------------
extern "C" void kernel_launch(void* const* d_in, const int* in_sizes, int n_in,
                              void* d_out, int out_size, void* d_ws, size_t ws_size,
                              hipStream_t stream) {
    const float* feat     = (const float*)d_in[0];
    const int*   e_feat   = (const int*)  d_in[1];
    const int*   src      = (const int*)  d_in[2];
    const int*   dst      = (const int*)  d_in[3];
    const float* fc_W     = (const float*)d_in[4];
    const float* edge_emb = (const float*)d_in[5];
    const float* w_r      = (const float*)d_in[6];
    const float* W1       = (const float*)d_in[7];
    const float* b1       = (const float*)d_in[8];
    const float* W2       = (const float*)d_in[9];
    const float* b2       = (const float*)d_in[10];
    const float* attn_l   = (const float*)d_in[11];
    const float* attn_r   = (const float*)d_in[12];
    const float* attn_e   = (const float*)d_in[13];

    char* ws = (char*)d_ws;
    unsigned short* featb  = (unsigned short*)(ws + 0);           // 15,360,000
    unsigned short* fsb    = (unsigned short*)(ws + 15360000);    // 15,360,000
    float*          el     = (float*)(ws + 30720000);             //    960,000
    float*          er     = (float*)(ws + 31680000);             //    960,000
    unsigned short* fcWb   = (unsigned short*)(ws + 32640000);    //    131,072
    float*          ee_tab = (float*)(ws + 32771072);             //        256
    int*            counts = (int*)(ws + 32771328);               //    120,000 (zeroed)
    int*            offs   = (int*)(ws + 32891328);               //    120,000
    int*            cursor = (int*)(ws + 33011328);               //    120,000
    int2*           sorted2= (int2*)(ws + 33131328);              //  3,840,000

    float* rst  = (float*)d_out;                     // [30000,8,32]
    float* aOut = rst + (size_t)N_NODES * HD;        // [480000,8]

    hipMemsetAsync(counts, 0, 120000, stream);
    ee_all<<<1, 1024, 0, stream>>>(edge_emb, W1, b1, W2, b2, attn_e, ee_tab);
    cvt_hist<<<2048, 256, 0, stream>>>(feat, fc_W, dst, featb, fcWb, counts);
    scan_kernel<<<1, 1024, 0, stream>>>(counts, offs, cursor);
    scatter_kernel<<<(N_EDGES + 255) / 256, 256, 0, stream>>>(dst, src, e_feat, cursor, sorted2);
    gemm_bf16<<<dim3((N_NODES + GBM - 1) / GBM, HD / GBN), 256, 0, stream>>>(
        featb, fcWb, attn_l, attn_r, fsb, el, er);
    node_fused<<<(N_NODES + 3) / 4, 256, 0, stream>>>(
        offs, counts, sorted2, el, er, ee_tab, w_r, fsb, rst, aOut);
}

// Round 8
// 248.779 us; speedup vs baseline: 2.1199x; 1.0323x over previous
//
#include <hip/hip_runtime.h>
#include <math.h>

#define N_NODES 30000
#define N_EDGES 480000
#define IN_FEATS 256
#define N_HEADS 8
#define OUT_FEATS 32
#define EDGE_FEATS 64
#define NUM_ETYPES 8
#define NEG_SLOPE 0.2f
#define HD 256  // N_HEADS*OUT_FEATS

typedef __bf16 bf16_t;
typedef bf16_t bf16x8 __attribute__((ext_vector_type(8)));
typedef float f32x4 __attribute__((ext_vector_type(4)));

__device__ __forceinline__ unsigned short f2bf(float f) {
    unsigned u = __float_as_uint(f);
    u += 0x7fffu + ((u >> 16) & 1u);   // round-to-nearest-even
    return (unsigned short)(u >> 16);
}
__device__ __forceinline__ float bf2f(unsigned short s) {
    return __uint_as_float(((unsigned)s) << 16);
}

__device__ __forceinline__ void gload_lds16(const void* g, void* l) {
    __builtin_amdgcn_global_load_lds(
        (const __attribute__((address_space(1))) unsigned int*)g,
        (__attribute__((address_space(3))) unsigned int*)l, 16, 0, 0);
}

// ---------------------------------------------------------------------------
// Kernel 1: fp32->bf16 conversion (feat, fc_W) + dst histogram, fused.
// ---------------------------------------------------------------------------
__global__ void cvt_hist(const float* __restrict__ feat, const float* __restrict__ fcW,
                         const int* __restrict__ dst,
                         unsigned short* __restrict__ featb, unsigned short* __restrict__ fcWb,
                         int* __restrict__ counts) {
    const int n1 = N_NODES * IN_FEATS / 4;      // 1,920,000 float4 groups
    const int n2 = IN_FEATS * HD / 4;           // 16,384
    const int tid0 = blockIdx.x * blockDim.x + threadIdx.x;
    const int stride = gridDim.x * blockDim.x;
    for (int i = tid0; i < n1 + n2; i += stride) {
        float4 v = (i < n1) ? ((const float4*)feat)[i] : ((const float4*)fcW)[i - n1];
        ushort4 o;
        o.x = f2bf(v.x); o.y = f2bf(v.y); o.z = f2bf(v.z); o.w = f2bf(v.w);
        if (i < n1) ((ushort4*)featb)[i] = o;
        else        ((ushort4*)fcWb)[i - n1] = o;
    }
    for (int e = tid0; e < N_EDGES; e += stride)
        atomicAdd(&counts[dst[e]], 1);
}

// ---------------------------------------------------------------------------
// Kernel 2: ee-table precompute + CSR exclusive scan, fused (one block).
//   phase 1: h1[t][r], M[h][k] -> LDS;  ee[t][h] = c[h] + dot(M, h1)
//   phase 2: LDS-staged exclusive scan of counts -> offsets/cursor
// LDS total ~135 KiB (single block, fits 160 KiB pool).
// ---------------------------------------------------------------------------
__global__ __launch_bounds__(1024) void ee_scan(
    const float* __restrict__ edge_emb,
    const float* __restrict__ W1, const float* __restrict__ b1,
    const float* __restrict__ W2, const float* __restrict__ b2,
    const float* __restrict__ attn_e, float* __restrict__ ee_tab,
    const int* __restrict__ counts, int* __restrict__ offsets,
    int* __restrict__ cursor) {
    __shared__ float h1S[1024];   // [t][r]
    __shared__ float MS[1024];    // [h][k]
    __shared__ int   buf[30720];
    __shared__ int   sums[1024];
    const int t0 = threadIdx.x;

    // ---- phase 1: ee table ----
    {
        int t = t0 >> 7, r = t0 & 127;
        const float4* Wv = (const float4*)(W1 + (size_t)r * EDGE_FEATS);
        const float4* Ev = (const float4*)(edge_emb + (size_t)t * EDGE_FEATS);
        float s = b1[r];
        #pragma unroll
        for (int q = 0; q < 16; q++) {
            float4 w = Wv[q], e = Ev[q];
            s += w.x * e.x + w.y * e.y + w.z * e.z + w.w * e.w;
        }
        h1S[t0] = fmaxf(s, 0.f);
    }
    {
        int h = t0 >> 7, k = t0 & 127;   // lanes consecutive in k -> coalesced W2
        float s = 0.f;
        #pragma unroll 8
        for (int f = 0; f < EDGE_FEATS; f++)
            s = fmaf(attn_e[h * EDGE_FEATS + f],
                     W2[(size_t)(h * EDGE_FEATS + f) * (2 * EDGE_FEATS) + k], s);
        MS[t0] = s;
    }
    __syncthreads();
    if (t0 < 64) {
        int t = t0 >> 3, h = t0 & 7;
        float s = 0.f;
        for (int f = 0; f < EDGE_FEATS; f++)
            s = fmaf(attn_e[h * EDGE_FEATS + f], b2[h * EDGE_FEATS + f], s);
        for (int k = 0; k < 2 * EDGE_FEATS; k++)
            s = fmaf(MS[h * 128 + k], h1S[t * 128 + k], s);
        ee_tab[t0] = s;
    }

    // ---- phase 2: scan ----
    for (int i = t0; i < 30720; i += 1024)
        buf[i] = (i < N_NODES) ? counts[i] : 0;
    __syncthreads();
    int s = 0;
    #pragma unroll
    for (int i = 0; i < 30; i++) s += buf[t0 * 30 + i];
    sums[t0] = s;
    __syncthreads();
    for (int off = 1; off < 1024; off <<= 1) {
        int v = (t0 >= off) ? sums[t0 - off] : 0;
        __syncthreads();
        sums[t0] += v;
        __syncthreads();
    }
    int run = sums[t0] - s;   // exclusive prefix of this chunk
    #pragma unroll
    for (int i = 0; i < 30; i++) {
        int c = buf[t0 * 30 + i];
        buf[t0 * 30 + i] = run;
        run += c;
    }
    __syncthreads();
    for (int i = t0; i < N_NODES; i += 1024) {
        int v = buf[i];
        offsets[i] = v; cursor[i] = v;
    }
}

// ---------------------------------------------------------------------------
// Kernel 3: bf16 MFMA GEMM  C = feat @ fc_W^T  -> bf16 feat_src [30000][256]
// 128x128 tile, 8 waves (2x4), double-buffered LDS, T3-minimal schedule:
// STAGE(next) issued BEFORE compute(cur); single __syncthreads per K-tile
// (compiler's pre-barrier vmcnt(0)/lgkmcnt(0) drain gives the sync).
// + fused el/er epilogue (each wave owns exactly one head's 32 cols).
// ---------------------------------------------------------------------------
#define GBM 128
#define GBN 128
#define GBK 64
__global__ __launch_bounds__(512) void gemm_bf16(const unsigned short* __restrict__ A,
                                                 const unsigned short* __restrict__ B,
                                                 const float* __restrict__ attn_l,
                                                 const float* __restrict__ attn_r,
                                                 unsigned short* __restrict__ Cb,
                                                 float* __restrict__ el,
                                                 float* __restrict__ er) {
    __shared__ __align__(16) unsigned char As[2][GBM * GBK * 2];  // 2 x 16 KiB
    __shared__ __align__(16) unsigned char Bs[2][GBN * GBK * 2];  // 2 x 16 KiB
    const int lane = threadIdx.x & 63;
    const int wid = threadIdx.x >> 6;     // 0..7
    const int wr = wid >> 2, wc = wid & 3;
    const int row0 = blockIdx.x * GBM;
    const int col0 = blockIdx.y * GBN;

    f32x4 acc[4][2] = {};

    // stage one K-tile into buffer b: A 16KB + B 16KB, 4 wave-issues of 1KB.
    // LDS linear [row][16B-chunk]; source chunk pre-swizzled (c ^ (row&7)).
    auto STAGE = [&](int b, int k0) {
        #pragma unroll
        for (int i = 0; i < 2; i++) {
            int loff = (wid * 2 + i) * 1024;           // wave-uniform base
            int row = (loff >> 7) + (lane >> 3);
            int c = lane & 7;
            int gr = row0 + row; if (gr > N_NODES - 1) gr = N_NODES - 1;
            int gc = k0 + ((c ^ (row & 7)) << 3);
            gload_lds16(A + (size_t)gr * IN_FEATS + gc, As[b] + loff + lane * 16);
        }
        #pragma unroll
        for (int i = 0; i < 2; i++) {
            int loff = (wid * 2 + i) * 1024;
            int row = (loff >> 7) + (lane >> 3);
            int c = lane & 7;
            int gc = k0 + ((c ^ (row & 7)) << 3);
            gload_lds16(B + (size_t)(col0 + row) * IN_FEATS + gc, Bs[b] + loff + lane * 16);
        }
    };

    STAGE(0, 0);
    __syncthreads();
    int cur = 0;
    #pragma unroll
    for (int kt = 0; kt < IN_FEATS / GBK; kt++) {
        if (kt < IN_FEATS / GBK - 1) STAGE(cur ^ 1, (kt + 1) * GBK);
        #pragma unroll
        for (int kk = 0; kk < 2; kk++) {
            bf16x8 af[4], bfr[2];
            const int g = kk * 4 + (lane >> 4);        // 16B k-chunk index
            #pragma unroll
            for (int fm = 0; fm < 4; fm++) {
                int row = wr * 64 + fm * 16 + (lane & 15);
                af[fm] = *(const bf16x8*)(As[cur] + row * 128 + ((g ^ (row & 7)) << 4));
            }
            #pragma unroll
            for (int fn = 0; fn < 2; fn++) {
                int row = wc * 32 + fn * 16 + (lane & 15);
                bfr[fn] = *(const bf16x8*)(Bs[cur] + row * 128 + ((g ^ (row & 7)) << 4));
            }
            #pragma unroll
            for (int fm = 0; fm < 4; fm++)
                #pragma unroll
                for (int fn = 0; fn < 2; fn++)
                    acc[fm][fn] = __builtin_amdgcn_mfma_f32_16x16x32_bf16(
                        af[fm], bfr[fn], acc[fm][fn], 0, 0, 0);
        }
        __syncthreads();   // drains this iter's staged loads + fences LDS reuse
        cur ^= 1;
    }
    // epilogue 1: C store. C/D map col=lane&15, row=(lane>>4)*4+r  [m89-verified]
    #pragma unroll
    for (int fm = 0; fm < 4; fm++) {
        #pragma unroll
        for (int r = 0; r < 4; r++) {
            int row = row0 + wr * 64 + fm * 16 + (lane >> 4) * 4 + r;
            if (row < N_NODES) {
                #pragma unroll
                for (int fn = 0; fn < 2; fn++) {
                    int col = col0 + wc * 32 + fn * 16 + (lane & 15);
                    Cb[(size_t)row * HD + col] = f2bf(acc[fm][fn][r]);
                }
            }
        }
    }
    // epilogue 2: el/er. This wave's 32 cols = head h's dims.
    const int h = col0 / 32 + wc;
    const int d0 = lane & 15;
    const float al0 = attn_l[h * 32 + d0],  al1 = attn_l[h * 32 + d0 + 16];
    const float ar0 = attn_r[h * 32 + d0],  ar1 = attn_r[h * 32 + d0 + 16];
    #pragma unroll
    for (int fm = 0; fm < 4; fm++) {
        #pragma unroll
        for (int r = 0; r < 4; r++) {
            float sl = acc[fm][0][r] * al0 + acc[fm][1][r] * al1;
            float sr = acc[fm][0][r] * ar0 + acc[fm][1][r] * ar1;
            #pragma unroll
            for (int m = 1; m <= 8; m <<= 1) {
                sl += __shfl_xor(sl, m);
                sr += __shfl_xor(sr, m);
            }
            int row = row0 + wr * 64 + fm * 16 + (lane >> 4) * 4 + r;
            if (d0 == 0 && row < N_NODES) {
                el[row * 8 + h] = sl;
                er[row * 8 + h] = sr;
            }
        }
    }
}

// ---------------------------------------------------------------------------
// Kernel 4: scatter packed CSR records {src*8+etype, eid} (one 8B store).
// ---------------------------------------------------------------------------
__global__ void scatter_kernel(const int* __restrict__ dst, const int* __restrict__ src,
                               const int* __restrict__ etype, int* __restrict__ cursor,
                               int2* __restrict__ sorted2) {
    int e = blockIdx.x * blockDim.x + threadIdx.x;
    if (e >= N_EDGES) return;
    int pos = atomicAdd(&cursor[dst[e]], 1);
    sorted2[pos] = make_int2(src[e] * 8 + etype[e], e);
}

// ---------------------------------------------------------------------------
// Kernel 5: fused per-node softmax + aggregation. One wave per dst node.
// Softmax lanes: (e_l = lane>>3, h = lane&7); aggregation: lane owns dims
// lane*4..lane*4+3 (head hq = lane>>3). r4-proven LDS-staged pass C.
// CSR record pre-packed: one coalesced 8B load gives (src, etype, eid).
// ---------------------------------------------------------------------------
__global__ __launch_bounds__(256) void node_fused(
    const int* __restrict__ offsets, const int* __restrict__ counts,
    const int2* __restrict__ sorted2,
    const float* __restrict__ el, const float* __restrict__ er,
    const float* __restrict__ ee_tab, const float* __restrict__ w_r,
    const unsigned short* __restrict__ fsb,
    float* __restrict__ rst, float* __restrict__ aOut) {
    __shared__ float eeS[64];
    __shared__ float wrS[8];
    __shared__ float lgS[4][64][8];   // per-wave logit cache, then 'a' staging
    __shared__ int   sS[4][8];
    if (threadIdx.x < 64) eeS[threadIdx.x] = ee_tab[threadIdx.x];
    if (threadIdx.x < 8)  wrS[threadIdx.x] = w_r[threadIdx.x];
    __syncthreads();
    const int wv = threadIdx.x >> 6, lane = threadIdx.x & 63;
    const int node = blockIdx.x * 4 + wv;
    if (node >= N_NODES) return;
    const int beg = offsets[node], cnt = counts[node];
    const int e_l = lane >> 3, h = lane & 7;
    const float er_v = er[node * 8 + h];
    const int nch = (cnt + 7) >> 3;

    // pass A: logits -> LDS cache, per-lane max
    float m = -1e30f;
    for (int ch = 0; ch < nch; ch++) {
        int idx = ch * 8 + e_l;
        float lg = -1e30f;
        if (idx < cnt) {
            int2 p = sorted2[beg + idx];
            int s = p.x >> 3, t = p.x & 7;
            float x = el[s * 8 + h] + er_v + eeS[t * 8 + h];
            x = (x > 0.f) ? x : NEG_SLOPE * x;
            lg = x * wrS[t];
        }
        if (idx < 64) lgS[wv][idx][h] = lg;
        m = fmaxf(m, lg);
    }
    m = fmaxf(m, __shfl_xor(m, 8));
    m = fmaxf(m, __shfl_xor(m, 16));
    m = fmaxf(m, __shfl_xor(m, 32));

    // pass B: denom
    float sum = 0.f;
    for (int ch = 0; ch < nch; ch++) {
        int idx = ch * 8 + e_l;
        if (idx < cnt) {
            float lg;
            if (idx < 64) lg = lgS[wv][idx][h];
            else {
                int2 p = sorted2[beg + idx];
                int s = p.x >> 3, t = p.x & 7;
                float x = el[s * 8 + h] + er_v + eeS[t * 8 + h];
                x = (x > 0.f) ? x : NEG_SLOPE * x;
                lg = x * wrS[t];
            }
            sum += __expf(lg - m);
        }
    }
    sum += __shfl_xor(sum, 8);
    sum += __shfl_xor(sum, 16);
    sum += __shfl_xor(sum, 32);
    const float inv = 1.f / sum;   // cnt==0 -> unused

    // pass C: a = ex*inv -> aOut + LDS stage; aggregate 8-edge chunk
    float acc0 = 0.f, acc1 = 0.f, acc2 = 0.f, acc3 = 0.f;
    const int hq = lane >> 3;       // aggregation head for dims lane*4..+3
    for (int ch = 0; ch < nch; ch++) {
        int idx = ch * 8 + e_l;
        float a = 0.f; int s = 0;
        if (idx < cnt) {
            int2 p = sorted2[beg + idx];
            s = p.x >> 3;
            float lg;
            if (idx < 64) lg = lgS[wv][idx][h];
            else {
                int t = p.x & 7;
                float x = el[s * 8 + h] + er_v + eeS[t * 8 + h];
                x = (x > 0.f) ? x : NEG_SLOPE * x;
                lg = x * wrS[t];
            }
            a = __expf(lg - m) * inv;
            aOut[(size_t)p.y * 8 + h] = a;
        }
        lgS[wv][idx & 63][h] = a;           // own slot (a=0 pad for idx>=cnt)
        if (h == 0) sS[wv][e_l] = s;        // s=0 pad for idx>=cnt
        int lim = cnt - ch * 8; if (lim > 8) lim = 8;
        for (int j = 0; j < lim; j++) {
            int sj = sS[wv][j];
            float av = lgS[wv][(ch * 8 + j) & 63][hq];
            ushort4 u = *(const ushort4*)(fsb + (size_t)sj * HD + lane * 4);
            acc0 = fmaf(av, bf2f(u.x), acc0);
            acc1 = fmaf(av, bf2f(u.y), acc1);
            acc2 = fmaf(av, bf2f(u.z), acc2);
            acc3 = fmaf(av, bf2f(u.w), acc3);
        }
    }
    *(float4*)(rst + (size_t)node * HD + lane * 4) = make_float4(acc0, acc1, acc2, acc3);
}

// ---------------------------------------------------------------------------
extern "C" void kernel_launch(void* const* d_in, const int* in_sizes, int n_in,
                              void* d_out, int out_size, void* d_ws, size_t ws_size,
                              hipStream_t stream) {
    const float* feat     = (const float*)d_in[0];
    const int*   e_feat   = (const int*)  d_in[1];
    const int*   src      = (const int*)  d_in[2];
    const int*   dst      = (const int*)  d_in[3];
    const float* fc_W     = (const float*)d_in[4];
    const float* edge_emb = (const float*)d_in[5];
    const float* w_r      = (const float*)d_in[6];
    const float* W1       = (const float*)d_in[7];
    const float* b1       = (const float*)d_in[8];
    const float* W2       = (const float*)d_in[9];
    const float* b2       = (const float*)d_in[10];
    const float* attn_l   = (const float*)d_in[11];
    const float* attn_r   = (const float*)d_in[12];
    const float* attn_e   = (const float*)d_in[13];

    char* ws = (char*)d_ws;
    unsigned short* featb  = (unsigned short*)(ws + 0);           // 15,360,000
    unsigned short* fsb    = (unsigned short*)(ws + 15360000);    // 15,360,000
    float*          el     = (float*)(ws + 30720000);             //    960,000
    float*          er     = (float*)(ws + 31680000);             //    960,000
    unsigned short* fcWb   = (unsigned short*)(ws + 32640000);    //    131,072
    float*          ee_tab = (float*)(ws + 32771072);             //        256
    int*            counts = (int*)(ws + 32771328);               //    120,000 (zeroed)
    int*            offs   = (int*)(ws + 32891328);               //    120,000
    int*            cursor = (int*)(ws + 33011328);               //    120,000
    int2*           sorted2= (int2*)(ws + 33131328);              //  3,840,000

    float* rst  = (float*)d_out;                     // [30000,8,32]
    float* aOut = rst + (size_t)N_NODES * HD;        // [480000,8]

    hipMemsetAsync(counts, 0, 120000, stream);
    cvt_hist<<<2048, 256, 0, stream>>>(feat, fc_W, dst, featb, fcWb, counts);
    ee_scan<<<1, 1024, 0, stream>>>(edge_emb, W1, b1, W2, b2, attn_e, ee_tab,
                                    counts, offs, cursor);
    scatter_kernel<<<(N_EDGES + 255) / 256, 256, 0, stream>>>(dst, src, e_feat, cursor, sorted2);
    gemm_bf16<<<dim3((N_NODES + GBM - 1) / GBM, HD / GBN), 512, 0, stream>>>(
        featb, fcWb, attn_l, attn_r, fsb, el, er);
    node_fused<<<(N_NODES + 3) / 4, 256, 0, stream>>>(
        offs, counts, sorted2, el, er, ee_tab, w_r, fsb, rst, aOut);
}

// Round 9
// 229.138 us; speedup vs baseline: 2.3016x; 1.0857x over previous
//
#include <hip/hip_runtime.h>
#include <math.h>

#define N_NODES 30000
#define N_EDGES 480000
#define IN_FEATS 256
#define N_HEADS 8
#define OUT_FEATS 32
#define EDGE_FEATS 64
#define NUM_ETYPES 8
#define NEG_SLOPE 0.2f
#define HD 256  // N_HEADS*OUT_FEATS
#define SCB 118 // scan blocks = ceil(30000/256)

typedef __bf16 bf16_t;
typedef bf16_t bf16x8 __attribute__((ext_vector_type(8)));
typedef float f32x4 __attribute__((ext_vector_type(4)));
typedef unsigned short ushort8_t __attribute__((ext_vector_type(8)));

__device__ __forceinline__ unsigned short f2bf(float f) {
    unsigned u = __float_as_uint(f);
    u += 0x7fffu + ((u >> 16) & 1u);   // round-to-nearest-even
    return (unsigned short)(u >> 16);
}
__device__ __forceinline__ float bf2f(unsigned short s) {
    return __uint_as_float(((unsigned)s) << 16);
}

__device__ __forceinline__ void gload_lds16(const void* g, void* l) {
    __builtin_amdgcn_global_load_lds(
        (const __attribute__((address_space(1))) unsigned int*)g,
        (__attribute__((address_space(3))) unsigned int*)l, 16, 0, 0);
}

// ---------------------------------------------------------------------------
// Kernel 1: dst histogram + fc_W fp32->bf16 (tiny). 1875 blocks x 256.
// ---------------------------------------------------------------------------
__global__ void hist_cvtW(const int* __restrict__ dst, const float* __restrict__ fcW,
                          int* __restrict__ counts, unsigned short* __restrict__ fcWb) {
    int i = blockIdx.x * 256 + threadIdx.x;
    if (i < IN_FEATS * HD / 4) {               // 16384 float4 groups
        float4 v = ((const float4*)fcW)[i];
        ushort4 o;
        o.x = f2bf(v.x); o.y = f2bf(v.y); o.z = f2bf(v.z); o.w = f2bf(v.w);
        ((ushort4*)fcWb)[i] = o;
    }
    if (i < N_EDGES) atomicAdd(&counts[dst[i]], 1);
}

// ---------------------------------------------------------------------------
// Kernel 2: ee precompute stage 1 (8 blocks x 256, r4-proven).
// ---------------------------------------------------------------------------
__global__ void ee_mid(const float* __restrict__ edge_emb,
                       const float* __restrict__ W1, const float* __restrict__ b1,
                       const float* __restrict__ W2, const float* __restrict__ attn_e,
                       float* __restrict__ h1_ws, float* __restrict__ M_ws) {
    int i = blockIdx.x * blockDim.x + threadIdx.x;   // 0..2047
    if (i < 1024) {
        int t = i >> 7, r = i & 127;
        const float4* Wv = (const float4*)(W1 + (size_t)r * EDGE_FEATS);
        const float4* Ev = (const float4*)(edge_emb + (size_t)t * EDGE_FEATS);
        float s = b1[r];
        #pragma unroll
        for (int q = 0; q < 16; q++) {
            float4 w = Wv[q], e = Ev[q];
            s += w.x * e.x + w.y * e.y + w.z * e.z + w.w * e.w;
        }
        h1_ws[i] = fmaxf(s, 0.f);
    } else {
        int m = i - 1024;
        int h = m >> 7, k = m & 127;     // lanes consecutive in k -> coalesced W2
        float s = 0.f;
        #pragma unroll 8
        for (int f = 0; f < EDGE_FEATS; f++)
            s = fmaf(attn_e[h * EDGE_FEATS + f],
                     W2[(size_t)(h * EDGE_FEATS + f) * (2 * EDGE_FEATS) + k], s);
        M_ws[m] = s;
    }
}

// ---------------------------------------------------------------------------
// Kernel 3: scanA — per-block partial sums of counts (118 x 256).
// ---------------------------------------------------------------------------
__global__ __launch_bounds__(256) void scanA(const int* __restrict__ counts,
                                             int* __restrict__ partials) {
    __shared__ int red[256];
    int i = blockIdx.x * 256 + threadIdx.x;
    red[threadIdx.x] = (i < N_NODES) ? counts[i] : 0;
    __syncthreads();
    #pragma unroll
    for (int off = 128; off > 0; off >>= 1) {
        if (threadIdx.x < off) red[threadIdx.x] += red[threadIdx.x + off];
        __syncthreads();
    }
    if (threadIdx.x == 0) partials[blockIdx.x] = red[0];
}

// ---------------------------------------------------------------------------
// Kernel 4: scanB (scan of 118 partials) + ee_fin, fused (1 block x 128).
// ---------------------------------------------------------------------------
__global__ void eefin_scanB(const int* __restrict__ partials, int* __restrict__ base,
                            const float* __restrict__ h1_ws, const float* __restrict__ M_ws,
                            const float* __restrict__ attn_e, const float* __restrict__ b2,
                            float* __restrict__ ee_tab) {
    __shared__ int ps[128];
    int t = threadIdx.x;
    int v = (t < SCB) ? partials[t] : 0;
    ps[t] = v;
    __syncthreads();
    for (int off = 1; off < 128; off <<= 1) {
        int u = (t >= off) ? ps[t - off] : 0;
        __syncthreads();
        ps[t] += u;
        __syncthreads();
    }
    if (t < SCB) base[t] = ps[t] - v;    // exclusive block base
    if (t < 64) {                        // ee_fin: ee[t][h]
        int tt = t >> 3, h = t & 7;
        float s = 0.f;
        for (int f = 0; f < EDGE_FEATS; f++)
            s = fmaf(attn_e[h * EDGE_FEATS + f], b2[h * EDGE_FEATS + f], s);
        for (int k = 0; k < 2 * EDGE_FEATS; k++)
            s = fmaf(M_ws[h * 128 + k], h1_ws[tt * 128 + k], s);
        ee_tab[t] = s;
    }
}

// ---------------------------------------------------------------------------
// Kernel 5: scanC — block-local scan + base, write offsets/cursor (118 x 256).
// ---------------------------------------------------------------------------
__global__ __launch_bounds__(256) void scanC(const int* __restrict__ counts,
                                             const int* __restrict__ base,
                                             int* __restrict__ offsets,
                                             int* __restrict__ cursor) {
    __shared__ int s[256];
    int t = threadIdx.x;
    int i = blockIdx.x * 256 + t;
    int v = (i < N_NODES) ? counts[i] : 0;
    s[t] = v;
    __syncthreads();
    for (int off = 1; off < 256; off <<= 1) {
        int u = (t >= off) ? s[t - off] : 0;
        __syncthreads();
        s[t] += u;
        __syncthreads();
    }
    int o = base[blockIdx.x] + s[t] - v;
    if (i < N_NODES) { offsets[i] = o; cursor[i] = o; }
}

// ---------------------------------------------------------------------------
// Kernel 6: scatter packed CSR records {src*8+etype, eid} (one 8B store).
// ---------------------------------------------------------------------------
__global__ void scatter_kernel(const int* __restrict__ dst, const int* __restrict__ src,
                               const int* __restrict__ etype, int* __restrict__ cursor,
                               int2* __restrict__ sorted2) {
    int e = blockIdx.x * blockDim.x + threadIdx.x;
    if (e >= N_EDGES) return;
    int pos = atomicAdd(&cursor[dst[e]], 1);
    sorted2[pos] = make_int2(src[e] * 8 + etype[e], e);
}

// ---------------------------------------------------------------------------
// Kernel 7: bf16 MFMA GEMM, A read as fp32 DIRECTLY (reg-staged cvt in-kernel,
// T14 issue-early/write-late), B via gload_lds. 128x256 tile (A read once),
// double-buffered, 8 waves (2x4), acc[4][4]. Fused el/er epilogue (each wave
// owns heads wc*2, wc*2+1).
// ---------------------------------------------------------------------------
#define GBM 128
#define GBN 256
#define GBK 64
#define NKT (IN_FEATS / GBK)   // 4
__global__ __launch_bounds__(512) void gemm_bf16(const float* __restrict__ A,
                                                 const unsigned short* __restrict__ B,
                                                 const float* __restrict__ attn_l,
                                                 const float* __restrict__ attn_r,
                                                 unsigned short* __restrict__ Cb,
                                                 float* __restrict__ el,
                                                 float* __restrict__ er) {
    __shared__ __align__(16) unsigned char As[2][GBM * GBK * 2];  // 2 x 16 KiB
    __shared__ __align__(16) unsigned char Bs[2][GBN * GBK * 2];  // 2 x 32 KiB
    const int tid = threadIdx.x;
    const int lane = tid & 63;
    const int wid = tid >> 6;            // 0..7
    const int wr = wid >> 2, wc = wid & 3;
    const int row0 = blockIdx.x * GBM;

    // A-stage mapping: 1024 16B-chunks (128 rows x 8 chunks), 2 per thread.
    int arow0 = tid >> 3,        ac0 = tid & 7;          // chunk tid
    int arow1 = (512 + tid) >> 3, ac1 = (512 + tid) & 7; // chunk 512+tid
    float4 av[2][2];

    f32x4 acc[4][4] = {};

    // prologue: stage K-tile 0
    #pragma unroll
    for (int i = 0; i < 4; i++) {
        int loff = (wid * 4 + i) * 1024;
        int row = (loff >> 7) + (lane >> 3);
        int c = lane & 7;
        int gc = ((c ^ (row & 7)) << 3);
        gload_lds16(B + (size_t)row * IN_FEATS + gc, Bs[0] + loff + lane * 16);
    }
    {
        int gr0 = row0 + arow0; if (gr0 > N_NODES - 1) gr0 = N_NODES - 1;
        int gr1 = row0 + arow1; if (gr1 > N_NODES - 1) gr1 = N_NODES - 1;
        const float4* p0 = (const float4*)(A + (size_t)gr0 * IN_FEATS + ac0 * 8);
        const float4* p1 = (const float4*)(A + (size_t)gr1 * IN_FEATS + ac1 * 8);
        av[0][0] = p0[0]; av[0][1] = p0[1];
        av[1][0] = p1[0]; av[1][1] = p1[1];
        ushort8_t u0, u1;
        u0[0]=f2bf(av[0][0].x); u0[1]=f2bf(av[0][0].y); u0[2]=f2bf(av[0][0].z); u0[3]=f2bf(av[0][0].w);
        u0[4]=f2bf(av[0][1].x); u0[5]=f2bf(av[0][1].y); u0[6]=f2bf(av[0][1].z); u0[7]=f2bf(av[0][1].w);
        u1[0]=f2bf(av[1][0].x); u1[1]=f2bf(av[1][0].y); u1[2]=f2bf(av[1][0].z); u1[3]=f2bf(av[1][0].w);
        u1[4]=f2bf(av[1][1].x); u1[5]=f2bf(av[1][1].y); u1[6]=f2bf(av[1][1].z); u1[7]=f2bf(av[1][1].w);
        *(ushort8_t*)(As[0] + arow0 * 128 + ((ac0 ^ (arow0 & 7)) << 4)) = u0;
        *(ushort8_t*)(As[0] + arow1 * 128 + ((ac1 ^ (arow1 & 7)) << 4)) = u1;
    }
    __syncthreads();

    int cur = 0;
    #pragma unroll
    for (int kt = 0; kt < NKT; kt++) {
        const int k1 = (kt + 1) * GBK;
        if (kt + 1 < NKT) {
            // issue next-tile loads EARLY (B direct-to-LDS, A to regs)
            #pragma unroll
            for (int i = 0; i < 4; i++) {
                int loff = (wid * 4 + i) * 1024;
                int row = (loff >> 7) + (lane >> 3);
                int c = lane & 7;
                int gc = k1 + ((c ^ (row & 7)) << 3);
                gload_lds16(B + (size_t)row * IN_FEATS + gc, Bs[cur ^ 1] + loff + lane * 16);
            }
            int gr0 = row0 + arow0; if (gr0 > N_NODES - 1) gr0 = N_NODES - 1;
            int gr1 = row0 + arow1; if (gr1 > N_NODES - 1) gr1 = N_NODES - 1;
            const float4* p0 = (const float4*)(A + (size_t)gr0 * IN_FEATS + k1 + ac0 * 8);
            const float4* p1 = (const float4*)(A + (size_t)gr1 * IN_FEATS + k1 + ac1 * 8);
            av[0][0] = p0[0]; av[0][1] = p0[1];
            av[1][0] = p1[0]; av[1][1] = p1[1];
        }
        // compute current buffer (hides the loads above)
        #pragma unroll
        for (int kk = 0; kk < 2; kk++) {
            bf16x8 af[4], bfr[4];
            const int g = kk * 4 + (lane >> 4);        // 16B k-chunk index
            #pragma unroll
            for (int fm = 0; fm < 4; fm++) {
                int row = wr * 64 + fm * 16 + (lane & 15);
                af[fm] = *(const bf16x8*)(As[cur] + row * 128 + ((g ^ (row & 7)) << 4));
            }
            #pragma unroll
            for (int fn = 0; fn < 4; fn++) {
                int row = wc * 64 + fn * 16 + (lane & 15);
                bfr[fn] = *(const bf16x8*)(Bs[cur] + row * 128 + ((g ^ (row & 7)) << 4));
            }
            #pragma unroll
            for (int fm = 0; fm < 4; fm++)
                #pragma unroll
                for (int fn = 0; fn < 4; fn++)
                    acc[fm][fn] = __builtin_amdgcn_mfma_f32_16x16x32_bf16(
                        af[fm], bfr[fn], acc[fm][fn], 0, 0, 0);
        }
        if (kt + 1 < NKT) {
            // write-late: cvt + ds_write into the other buffer
            ushort8_t u0, u1;
            u0[0]=f2bf(av[0][0].x); u0[1]=f2bf(av[0][0].y); u0[2]=f2bf(av[0][0].z); u0[3]=f2bf(av[0][0].w);
            u0[4]=f2bf(av[0][1].x); u0[5]=f2bf(av[0][1].y); u0[6]=f2bf(av[0][1].z); u0[7]=f2bf(av[0][1].w);
            u1[0]=f2bf(av[1][0].x); u1[1]=f2bf(av[1][0].y); u1[2]=f2bf(av[1][0].z); u1[3]=f2bf(av[1][0].w);
            u1[4]=f2bf(av[1][1].x); u1[5]=f2bf(av[1][1].y); u1[6]=f2bf(av[1][1].z); u1[7]=f2bf(av[1][1].w);
            *(ushort8_t*)(As[cur ^ 1] + arow0 * 128 + ((ac0 ^ (arow0 & 7)) << 4)) = u0;
            *(ushort8_t*)(As[cur ^ 1] + arow1 * 128 + ((ac1 ^ (arow1 & 7)) << 4)) = u1;
        }
        __syncthreads();   // drains gload_lds (vmcnt) + ds_writes (lgkm)
        cur ^= 1;
    }

    // epilogue 1: C store. C/D map col=lane&15, row=(lane>>4)*4+r  [m89-verified]
    #pragma unroll
    for (int fm = 0; fm < 4; fm++) {
        #pragma unroll
        for (int r = 0; r < 4; r++) {
            int row = row0 + wr * 64 + fm * 16 + (lane >> 4) * 4 + r;
            if (row < N_NODES) {
                #pragma unroll
                for (int fn = 0; fn < 4; fn++) {
                    int col = wc * 64 + fn * 16 + (lane & 15);
                    Cb[(size_t)row * HD + col] = f2bf(acc[fm][fn][r]);
                }
            }
        }
    }
    // epilogue 2: el/er. Wave covers heads wc*2 (fn 0,1) and wc*2+1 (fn 2,3).
    const int d0 = lane & 15;
    #pragma unroll
    for (int hp = 0; hp < 2; hp++) {
        const int h = wc * 2 + hp;
        const float al0 = attn_l[h * 32 + d0], al1 = attn_l[h * 32 + d0 + 16];
        const float ar0 = attn_r[h * 32 + d0], ar1 = attn_r[h * 32 + d0 + 16];
        #pragma unroll
        for (int fm = 0; fm < 4; fm++) {
            #pragma unroll
            for (int r = 0; r < 4; r++) {
                float sl = acc[fm][2 * hp][r] * al0 + acc[fm][2 * hp + 1][r] * al1;
                float sr = acc[fm][2 * hp][r] * ar0 + acc[fm][2 * hp + 1][r] * ar1;
                #pragma unroll
                for (int m = 1; m <= 8; m <<= 1) {
                    sl += __shfl_xor(sl, m);
                    sr += __shfl_xor(sr, m);
                }
                int row = row0 + wr * 64 + fm * 16 + (lane >> 4) * 4 + r;
                if (d0 == 0 && row < N_NODES) {
                    el[row * 8 + h] = sl;
                    er[row * 8 + h] = sr;
                }
            }
        }
    }
}

// ---------------------------------------------------------------------------
// Kernel 8: fused per-node softmax + aggregation (r7/r8-proven form).
// ---------------------------------------------------------------------------
__global__ __launch_bounds__(256) void node_fused(
    const int* __restrict__ offsets, const int* __restrict__ counts,
    const int2* __restrict__ sorted2,
    const float* __restrict__ el, const float* __restrict__ er,
    const float* __restrict__ ee_tab, const float* __restrict__ w_r,
    const unsigned short* __restrict__ fsb,
    float* __restrict__ rst, float* __restrict__ aOut) {
    __shared__ float eeS[64];
    __shared__ float wrS[8];
    __shared__ float lgS[4][64][8];   // per-wave logit cache, then 'a' staging
    __shared__ int   sS[4][8];
    if (threadIdx.x < 64) eeS[threadIdx.x] = ee_tab[threadIdx.x];
    if (threadIdx.x < 8)  wrS[threadIdx.x] = w_r[threadIdx.x];
    __syncthreads();
    const int wv = threadIdx.x >> 6, lane = threadIdx.x & 63;
    const int node = blockIdx.x * 4 + wv;
    if (node >= N_NODES) return;
    const int beg = offsets[node], cnt = counts[node];
    const int e_l = lane >> 3, h = lane & 7;
    const float er_v = er[node * 8 + h];
    const int nch = (cnt + 7) >> 3;

    // pass A: logits -> LDS cache, per-lane max
    float m = -1e30f;
    for (int ch = 0; ch < nch; ch++) {
        int idx = ch * 8 + e_l;
        float lg = -1e30f;
        if (idx < cnt) {
            int2 p = sorted2[beg + idx];
            int s = p.x >> 3, t = p.x & 7;
            float x = el[s * 8 + h] + er_v + eeS[t * 8 + h];
            x = (x > 0.f) ? x : NEG_SLOPE * x;
            lg = x * wrS[t];
        }
        if (idx < 64) lgS[wv][idx][h] = lg;
        m = fmaxf(m, lg);
    }
    m = fmaxf(m, __shfl_xor(m, 8));
    m = fmaxf(m, __shfl_xor(m, 16));
    m = fmaxf(m, __shfl_xor(m, 32));

    // pass B: denom
    float sum = 0.f;
    for (int ch = 0; ch < nch; ch++) {
        int idx = ch * 8 + e_l;
        if (idx < cnt) {
            float lg;
            if (idx < 64) lg = lgS[wv][idx][h];
            else {
                int2 p = sorted2[beg + idx];
                int s = p.x >> 3, t = p.x & 7;
                float x = el[s * 8 + h] + er_v + eeS[t * 8 + h];
                x = (x > 0.f) ? x : NEG_SLOPE * x;
                lg = x * wrS[t];
            }
            sum += __expf(lg - m);
        }
    }
    sum += __shfl_xor(sum, 8);
    sum += __shfl_xor(sum, 16);
    sum += __shfl_xor(sum, 32);
    const float inv = 1.f / sum;   // cnt==0 -> unused

    // pass C: a = ex*inv -> aOut + LDS stage; aggregate 8-edge chunk
    float acc0 = 0.f, acc1 = 0.f, acc2 = 0.f, acc3 = 0.f;
    const int hq = lane >> 3;       // aggregation head for dims lane*4..+3
    for (int ch = 0; ch < nch; ch++) {
        int idx = ch * 8 + e_l;
        float a = 0.f; int s = 0;
        if (idx < cnt) {
            int2 p = sorted2[beg + idx];
            s = p.x >> 3;
            float lg;
            if (idx < 64) lg = lgS[wv][idx][h];
            else {
                int t = p.x & 7;
                float x = el[s * 8 + h] + er_v + eeS[t * 8 + h];
                x = (x > 0.f) ? x : NEG_SLOPE * x;
                lg = x * wrS[t];
            }
            a = __expf(lg - m) * inv;
            aOut[(size_t)p.y * 8 + h] = a;
        }
        lgS[wv][idx & 63][h] = a;           // own slot (a=0 pad for idx>=cnt)
        if (h == 0) sS[wv][e_l] = s;        // s=0 pad for idx>=cnt
        int lim = cnt - ch * 8; if (lim > 8) lim = 8;
        for (int j = 0; j < lim; j++) {
            int sj = sS[wv][j];
            float av = lgS[wv][(ch * 8 + j) & 63][hq];
            ushort4 u = *(const ushort4*)(fsb + (size_t)sj * HD + lane * 4);
            acc0 = fmaf(av, bf2f(u.x), acc0);
            acc1 = fmaf(av, bf2f(u.y), acc1);
            acc2 = fmaf(av, bf2f(u.z), acc2);
            acc3 = fmaf(av, bf2f(u.w), acc3);
        }
    }
    *(float4*)(rst + (size_t)node * HD + lane * 4) = make_float4(acc0, acc1, acc2, acc3);
}

// ---------------------------------------------------------------------------
extern "C" void kernel_launch(void* const* d_in, const int* in_sizes, int n_in,
                              void* d_out, int out_size, void* d_ws, size_t ws_size,
                              hipStream_t stream) {
    const float* feat     = (const float*)d_in[0];
    const int*   e_feat   = (const int*)  d_in[1];
    const int*   src      = (const int*)  d_in[2];
    const int*   dst      = (const int*)  d_in[3];
    const float* fc_W     = (const float*)d_in[4];
    const float* edge_emb = (const float*)d_in[5];
    const float* w_r      = (const float*)d_in[6];
    const float* W1       = (const float*)d_in[7];
    const float* b1       = (const float*)d_in[8];
    const float* W2       = (const float*)d_in[9];
    const float* b2       = (const float*)d_in[10];
    const float* attn_l   = (const float*)d_in[11];
    const float* attn_r   = (const float*)d_in[12];
    const float* attn_e   = (const float*)d_in[13];

    char* ws = (char*)d_ws;
    unsigned short* fsb     = (unsigned short*)(ws + 0);          // 15,360,000
    float*          el      = (float*)(ws + 15360000);            //    960,000
    float*          er      = (float*)(ws + 16320000);            //    960,000
    unsigned short* fcWb    = (unsigned short*)(ws + 17280000);   //    131,072
    float*          ee_tab  = (float*)(ws + 17411072);            //        256
    int*            counts  = (int*)(ws + 17411328);              //    120,000 (zeroed)
    int*            offs    = (int*)(ws + 17531328);              //    120,000
    int*            cursor  = (int*)(ws + 17651328);              //    120,000
    int2*           sorted2 = (int2*)(ws + 17771328);             //  3,840,000
    float*          h1_ws   = (float*)(ws + 21611328);            //      4,096
    float*          M_ws    = (float*)(ws + 21615424);            //      4,096
    int*            partials= (int*)(ws + 21619520);              //        512
    int*            base    = (int*)(ws + 21620032);              //        512

    float* rst  = (float*)d_out;                     // [30000,8,32]
    float* aOut = rst + (size_t)N_NODES * HD;        // [480000,8]

    hipMemsetAsync(counts, 0, 120000, stream);
    hist_cvtW<<<(N_EDGES + 255) / 256, 256, 0, stream>>>(dst, fc_W, counts, fcWb);
    ee_mid<<<8, 256, 0, stream>>>(edge_emb, W1, b1, W2, attn_e, h1_ws, M_ws);
    scanA<<<SCB, 256, 0, stream>>>(counts, partials);
    eefin_scanB<<<1, 128, 0, stream>>>(partials, base, h1_ws, M_ws, attn_e, b2, ee_tab);
    scanC<<<SCB, 256, 0, stream>>>(counts, base, offs, cursor);
    scatter_kernel<<<(N_EDGES + 255) / 256, 256, 0, stream>>>(dst, src, e_feat, cursor, sorted2);
    gemm_bf16<<<(N_NODES + GBM - 1) / GBM, 512, 0, stream>>>(
        feat, fcWb, attn_l, attn_r, fsb, el, er);
    node_fused<<<(N_NODES + 3) / 4, 256, 0, stream>>>(
        offs, counts, sorted2, el, er, ee_tab, w_r, fsb, rst, aOut);
}